// Round 2
// baseline (2962.099 us; speedup 1.0000x reference)
//
#include <hip/hip_runtime.h>
#include <hip/hip_bf16.h>
#include <math.h>

#define BB 64

// workspace layout (in floats)
#define WS_BNA   4
#define WS_BNB   132
#define WS_FTAB  260
#define WS_ROWW  780
#define WS_SLRS  1300
#define WS_CONV  1376
#define SZ_CONV  2121728   // 64*128*259
#define SZ_PBUF  1056768   // 64*64*258 (max intermediate pooled)
#define WS_PA1   (WS_CONV + SZ_CONV)
#define WS_PA2   (WS_PA1 + SZ_PBUF)
#define WS_PB1   (WS_PA2 + SZ_PBUF)
#define WS_PB2   (WS_PB1 + SZ_PBUF)
#define WS_ZT    (WS_PB2 + SZ_PBUF)
#define SZ_ZT    2129920   // 64*260*128
#define WS_TOTAL (WS_ZT + SZ_ZT)

// d_out layout (floats)
#define O_LG1  0
#define O_LG2  320
#define O_A1   640
#define O_A2   (640 + 1064960)
#define O_LOSS (O_A2 + 1064960)

__global__ void init_k(double* acc, const float* __restrict__ sl, float* __restrict__ slrs) {
  if (threadIdx.x == 0) *acc = 0.0;
  int r = threadIdx.x;  // 64 threads
  float s = 0.f;
  for (int c = 0; c < 64; ++c) s += sl[r * 64 + c];
  slrs[r] = s;
}

// conv1d K=8 pad=4, 4 output channels per thread
__global__ void conv_k(const float* __restrict__ x, const float* __restrict__ w,
                       float* __restrict__ y, int Cin, int Cout, int Lin, int Lc) {
  int j = blockIdx.x * blockDim.x + threadIdx.x;
  if (j >= Lc) return;
  int nq = Cout >> 2;
  int oq = blockIdx.y % nq;
  int b  = blockIdx.y / nq;
  int o0 = oq << 2;
  const float* xb = x + (size_t)b * Cin * Lin;
  const float* wr = w + (size_t)o0 * Cin * 8;
  int ws8 = Cin * 8;
  float a0 = 0.f, a1 = 0.f, a2 = 0.f, a3 = 0.f;
  bool interior = (j >= 4) && (j <= Lin - 4);
  for (int i = 0; i < Cin; ++i) {
    float xv[8];
    const float* xr = xb + (size_t)i * Lin + (j - 4);
    if (interior) {
#pragma unroll
      for (int k = 0; k < 8; ++k) xv[k] = xr[k];
    } else {
#pragma unroll
      for (int k = 0; k < 8; ++k) {
        int p = j + k - 4;
        xv[k] = (p >= 0 && p < Lin) ? xb[(size_t)i * Lin + p] : 0.f;
      }
    }
    const float* w0 = wr + i * 8;
#pragma unroll
    for (int k = 0; k < 8; ++k) {
      float xk = xv[k];
      a0 = fmaf(w0[k          ], xk, a0);
      a1 = fmaf(w0[k +     ws8], xk, a1);
      a2 = fmaf(w0[k + 2 * ws8], xk, a2);
      a3 = fmaf(w0[k + 3 * ws8], xk, a3);
    }
  }
  size_t base = ((size_t)b * Cout + o0) * Lc + j;
  y[base] = a0; y[base + Lc] = a1; y[base + 2 * (size_t)Lc] = a2; y[base + 3 * (size_t)Lc] = a3;
}

// BN batch stats per channel over (B, Lc); folds to A*x+B
__global__ void stats_k(const float* __restrict__ conv, const float* __restrict__ g,
                        const float* __restrict__ beta, float* __restrict__ bnA,
                        float* __restrict__ bnB, int C, int Lc) {
  int c = blockIdx.x;
  int n = BB * Lc;
  float s = 0.f, s2 = 0.f;
  for (int u = threadIdx.x; u < n; u += blockDim.x) {
    int b = u / Lc, j = u - b * Lc;
    float v = conv[((size_t)b * C + c) * Lc + j];
    s += v; s2 = fmaf(v, v, s2);
  }
#pragma unroll
  for (int off = 32; off; off >>= 1) { s += __shfl_down(s, off); s2 += __shfl_down(s2, off); }
  __shared__ float ps[4], ps2[4];
  if ((threadIdx.x & 63) == 0) { ps[threadIdx.x >> 6] = s; ps2[threadIdx.x >> 6] = s2; }
  __syncthreads();
  if (threadIdx.x == 0) {
    float S = ps[0] + ps[1] + ps[2] + ps[3];
    float S2 = ps2[0] + ps2[1] + ps2[2] + ps2[3];
    float mu = S / n;
    float var = S2 / n - mu * mu;
    float A = g[c] * rsqrtf(var + 1e-5f);
    bnA[c] = A;
    bnB[c] = beta[c] - mu * A;
  }
}

// BN-apply + ReLU + maxpool(2,2,pad1); writes pooled [B,C,T] and z [B,2T,C] (transposed via LDS)
__global__ void pool_k(const float* __restrict__ conv, const float* __restrict__ bnA,
                       const float* __restrict__ bnB, float* __restrict__ pooled,
                       float* __restrict__ zt, int C, int Lc, int Tout, int zoff) {
  __shared__ float tile[32][33];
  int b = blockIdx.z;
  int c0 = blockIdx.y * 32;
  int t0 = blockIdx.x * 32;
  int tx = threadIdx.x;  // 32
  int ty = threadIdx.y;  // 8
#pragma unroll
  for (int q = 0; q < 4; ++q) {
    int c = c0 + ty + q * 8;
    int t = t0 + tx;
    float v = 0.f;
    if (t < Tout) {
      const float* row = conv + ((size_t)b * C + c) * Lc;
      float A = bnA[c], Bb = bnB[c];
      v = -3.0e38f;
      int p0 = 2 * t - 1;
      if (p0 >= 0) v = fmaxf(v, fmaxf(fmaf(A, row[p0], Bb), 0.f));
      int p1 = 2 * t;
      if (p1 < Lc) v = fmaxf(v, fmaxf(fmaf(A, row[p1], Bb), 0.f));
      pooled[((size_t)b * C + c) * Tout + t] = v;
    }
    tile[ty + q * 8][tx] = v;
  }
  __syncthreads();
  int T2 = 2 * Tout;
#pragma unroll
  for (int q = 0; q < 4; ++q) {
    int t = t0 + ty + q * 8;
    int c = c0 + tx;
    if (t < Tout) zt[((size_t)b * T2 + zoff + t) * (size_t)C + c] = tile[tx][ty + q * 8];
  }
}

// timelag table (f64, thresholded like numpy) + row weight-sums
__global__ void ftab_k(float* __restrict__ ftab, float* __restrict__ roww, int T, float sigma) {
  __shared__ float fs[520];
  for (int d = threadIdx.x; d < T; d += blockDim.x) {
    double mm = 2.0 / (1.0 + exp((double)d * (double)sigma));
    float f = (mm < 1e-6) ? 0.f : (float)mm;
    ftab[d] = f; fs[d] = f;
  }
  __syncthreads();
  for (int i = threadIdx.x; i < T; i += blockDim.x) {
    float s = 0.f;
    for (int j = 0; j < T; ++j) { int d = i - j; d = d < 0 ? -d : d; s += fs[d]; }
    roww[i] = 2.f * s - fs[0];
  }
}

__device__ __forceinline__ void block_acc(float rl, double scale, double* acc) {
#pragma unroll
  for (int off = 32; off; off >>= 1) rl += __shfl_down(rl, off);
  __shared__ float part[2];
  if ((threadIdx.x & 63) == 0) part[threadIdx.x >> 6] = rl;
  __syncthreads();
  if (threadIdx.x == 0) atomicAdd(acc, (double)(part[0] + part[1]) * scale);
}

// temporal contrastive: one thread per row i of [B, 2T]; columns broadcast from global
template <int C>
__global__ void temp_loss_k(const float* __restrict__ zt, const float* __restrict__ ftab,
                            const float* __restrict__ roww, int T, double scale, double* acc) {
  __shared__ float fsh[520];
  int T2 = 2 * T;
  for (int u = threadIdx.x; u < T; u += blockDim.x) fsh[u] = ftab[u];
  int b = blockIdx.y;
  int i = blockIdx.x * blockDim.x + threadIdx.x;
  const float* zb = zt + (size_t)b * T2 * C;
  float4 zr[C / 4];
  bool act = i < T2;
  int ii = 0; float rw = 0.f;
  if (act) {
    const float4* zp = (const float4*)(zb + (size_t)i * C);
#pragma unroll
    for (int q = 0; q < C / 4; ++q) zr[q] = zp[q];
    ii = (i < T) ? i : i - T;
    rw = roww[ii];
  }
  __syncthreads();
  float m = -3.0e38f, se = 0.f, wdot = 0.f;
  if (act) {
    for (int j = 0; j < T2; ++j) {
      if (j == i) continue;
      const float4* cp = (const float4*)(zb + (size_t)j * C);
      float s = 0.f;
#pragma unroll
      for (int q = 0; q < C / 4; ++q) {
        float4 cv = cp[q];
        s += zr[q].x * cv.x + zr[q].y * cv.y + zr[q].z * cv.z + zr[q].w * cv.w;
      }
      int jj = (j < T) ? j : j - T;
      int dd = ii - jj; dd = dd < 0 ? -dd : dd;
      if (dd < 16) wdot = fmaf(fsh[dd], s, wdot);   // f(d)==0 beyond d=7 (thresholded)
      float mn = fmaxf(m, s);
      se = se * __expf(m - mn) + __expf(s - mn);
      m = mn;
    }
  }
  float rl = act ? (rw * (m + __logf(se)) - wdot) : 0.f;
  block_acc(rl, scale, acc);
}

// instance contrastive: block per t, thread per row r of [2B]; weight = sl[r%B, c%B]
template <int C>
__global__ void inst_loss_k(const float* __restrict__ zt, const float* __restrict__ sl,
                            const float* __restrict__ slrs, int T, double scale, double* acc) {
  __shared__ float ssh[64][65];
  int t = blockIdx.x;
  int r = threadIdx.x;  // 0..127
  for (int u = threadIdx.x; u < 64 * 64; u += blockDim.x) ssh[u >> 6][u & 63] = sl[u];
  int b = r & 63;
  int zrow_t = (r < 64) ? t : (T + t);
  const float4* zp = (const float4*)(zt + ((size_t)b * 2 * T + zrow_t) * (size_t)C);
  float4 zr[C / 4];
#pragma unroll
  for (int q = 0; q < C / 4; ++q) zr[q] = zp[q];
  __syncthreads();
  float m = -3.0e38f, se = 0.f, wdot = 0.f;
  for (int j = 0; j < 128; ++j) {
    if (j == r) continue;
    int jb = j & 63;
    int jt = (j < 64) ? t : (T + t);
    const float4* cp = (const float4*)(zt + ((size_t)jb * 2 * T + jt) * (size_t)C);
    float s = 0.f;
#pragma unroll
    for (int q = 0; q < C / 4; ++q) {
      float4 cv = cp[q];
      s += zr[q].x * cv.x + zr[q].y * cv.y + zr[q].z * cv.z + zr[q].w * cv.w;
    }
    wdot = fmaf(ssh[b][jb], s, wdot);
    float mn = fmaxf(m, s);
    se = se * __expf(m - mn) + __expf(s - mn);
    m = mn;
  }
  float rl = (2.f * slrs[b] - ssh[b][b]) * (m + __logf(se)) - wdot;
  block_acc(rl, scale, acc);
}

// final FC: lg[n,:] = a[n,:] @ wf + bf ; block per n
__global__ void fc_k(const float* __restrict__ a, const float* __restrict__ wf,
                     const float* __restrict__ bf, float* __restrict__ lg) {
  int n = blockIdx.x;
  float accv[5] = {0.f, 0.f, 0.f, 0.f, 0.f};
  for (int f = threadIdx.x; f < 16640; f += blockDim.x) {
    float av = a[(size_t)n * 16640 + f];
    const float* wr = wf + (size_t)f * 5;
#pragma unroll
    for (int k = 0; k < 5; ++k) accv[k] = fmaf(av, wr[k], accv[k]);
  }
  __shared__ float red[4][5];
#pragma unroll
  for (int k = 0; k < 5; ++k) {
    float v = accv[k];
#pragma unroll
    for (int off = 32; off; off >>= 1) v += __shfl_down(v, off);
    if ((threadIdx.x & 63) == 0) red[threadIdx.x >> 6][k] = v;
  }
  __syncthreads();
  if (threadIdx.x == 0) {
#pragma unroll
    for (int k = 0; k < 5; ++k) lg[n * 5 + k] = red[0][k] + red[1][k] + red[2][k] + red[3][k] + bf[k];
  }
}

__global__ void fin_k(const double* acc, float* out_loss) { *out_loss = (float)(*acc); }

extern "C" void kernel_launch(void* const* d_in, const int* in_sizes, int n_in,
                              void* d_out, int out_size, void* d_ws, size_t ws_size,
                              hipStream_t stream) {
  const float* aug[2] = {(const float*)d_in[0], (const float*)d_in[1]};
  const float* sl = (const float*)d_in[2];
  const float* wconv[3] = {(const float*)d_in[3], (const float*)d_in[6], (const float*)d_in[9]};
  const float* gam[3]   = {(const float*)d_in[4], (const float*)d_in[7], (const float*)d_in[10]};
  const float* bet[3]   = {(const float*)d_in[5], (const float*)d_in[8], (const float*)d_in[11]};
  const float* wf = (const float*)d_in[12];
  const float* bf = (const float*)d_in[13];
  float* out = (float*)d_out;
  float* ws = (float*)d_ws;
  if (ws_size < (size_t)WS_TOTAL * sizeof(float)) return;  // need ~34 MB scratch

  double* acc = (double*)ws;
  float* bnA = ws + WS_BNA;
  float* bnB = ws + WS_BNB;
  float* ftab = ws + WS_FTAB;
  float* roww = ws + WS_ROWW;
  float* slrs = ws + WS_SLRS;
  float* convb = ws + WS_CONV;
  float* zt = ws + WS_ZT;

  const int Cin[3]  = {1, 32, 64};
  const int Cout[3] = {32, 64, 128};
  const int Lin[3]  = {1024, 513, 258};
  const int Lc[3]   = {1025, 514, 259};
  const int Tarr[3] = {513, 258, 130};
  const float sig[3] = {2.f, 4.f, 8.f};

  float* A1 = out + O_A1;
  float* A2 = out + O_A2;

  init_k<<<1, 64, 0, stream>>>(acc, sl, slrs);

  for (int d = 0; d < 3; ++d) {
    int T = Tarr[d];
    for (int s = 0; s < 2; ++s) {
      const float* xin;
      float* pdst;
      if (d == 0)      { xin = aug[s];                               pdst = (s == 0) ? ws + WS_PA1 : ws + WS_PB1; }
      else if (d == 1) { xin = (s == 0) ? ws + WS_PA1 : ws + WS_PB1; pdst = (s == 0) ? ws + WS_PA2 : ws + WS_PB2; }
      else             { xin = (s == 0) ? ws + WS_PA2 : ws + WS_PB2; pdst = (s == 0) ? A1 : A2; }

      dim3 cg((Lc[d] + 255) / 256, BB * (Cout[d] / 4));
      conv_k<<<cg, 256, 0, stream>>>(xin, wconv[d], convb, Cin[d], Cout[d], Lin[d], Lc[d]);
      stats_k<<<Cout[d], 256, 0, stream>>>(convb, gam[d], bet[d], bnA, bnB, Cout[d], Lc[d]);
      dim3 pg((T + 31) / 32, Cout[d] / 32, BB);
      pool_k<<<pg, dim3(32, 8), 0, stream>>>(convb, bnA, bnB, pdst, zt, Cout[d], Lc[d], T, s * T);
    }
    ftab_k<<<1, 256, 0, stream>>>(ftab, roww, T, sig[d]);
    double scale = 0.5 / (128.0 * (double)T);  // (1-LAM)=LAM=0.5, /(2*B*T)
    dim3 tg((2 * T + 127) / 128, BB);
    switch (d) {
      case 0:
        temp_loss_k<32><<<tg, 128, 0, stream>>>(zt, ftab, roww, T, scale, acc);
        inst_loss_k<32><<<T, 128, 0, stream>>>(zt, sl, slrs, T, scale, acc);
        break;
      case 1:
        temp_loss_k<64><<<tg, 128, 0, stream>>>(zt, ftab, roww, T, scale, acc);
        inst_loss_k<64><<<T, 128, 0, stream>>>(zt, sl, slrs, T, scale, acc);
        break;
      default:
        temp_loss_k<128><<<tg, 128, 0, stream>>>(zt, ftab, roww, T, scale, acc);
        inst_loss_k<128><<<T, 128, 0, stream>>>(zt, sl, slrs, T, scale, acc);
        break;
    }
  }
  fc_k<<<64, 256, 0, stream>>>(A1, wf, bf, out + O_LG1);
  fc_k<<<64, 256, 0, stream>>>(A2, wf, bf, out + O_LG2);
  fin_k<<<1, 1, 0, stream>>>(acc, out + O_LOSS);
}

// Round 3
// 1249.107 us; speedup vs baseline: 2.3714x; 2.3714x over previous
//
#include <hip/hip_runtime.h>
#include <hip/hip_bf16.h>
#include <math.h>

#define BB 64

// workspace layout (in floats)
#define WS_BNA   4
#define WS_BNB   132
#define WS_FTAB  260
#define WS_ROWW  780
#define WS_SLRS  1300
#define WS_CONV  1376
#define SZ_CONV  2121728   // 64*128*259
#define SZ_PBUF  1056768   // 64*64*258 (max intermediate pooled)
#define WS_PA1   (WS_CONV + SZ_CONV)
#define WS_PA2   (WS_PA1 + SZ_PBUF)
#define WS_PB1   (WS_PA2 + SZ_PBUF)
#define WS_PB2   (WS_PB1 + SZ_PBUF)
#define WS_ZT    (WS_PB2 + SZ_PBUF)
#define SZ_ZT    2129920   // 64*260*128
#define WS_TOTAL (WS_ZT + SZ_ZT)

// d_out layout (floats)
#define O_LG1  0
#define O_LG2  320
#define O_A1   640
#define O_A2   (640 + 1064960)
#define O_LOSS (O_A2 + 1064960)

__global__ void init_k(double* acc, const float* __restrict__ sl, float* __restrict__ slrs) {
  if (threadIdx.x == 0) *acc = 0.0;
  int r = threadIdx.x;  // 64 threads
  float s = 0.f;
  for (int c = 0; c < 64; ++c) s += sl[r * 64 + c];
  slrs[r] = s;
}

// conv1d K=8 pad=4, 4 output channels per thread
__global__ void conv_k(const float* __restrict__ x, const float* __restrict__ w,
                       float* __restrict__ y, int Cin, int Cout, int Lin, int Lc) {
  int j = blockIdx.x * blockDim.x + threadIdx.x;
  if (j >= Lc) return;
  int nq = Cout >> 2;
  int oq = blockIdx.y % nq;
  int b  = blockIdx.y / nq;
  int o0 = oq << 2;
  const float* xb = x + (size_t)b * Cin * Lin;
  const float* wr = w + (size_t)o0 * Cin * 8;
  int ws8 = Cin * 8;
  float a0 = 0.f, a1 = 0.f, a2 = 0.f, a3 = 0.f;
  bool interior = (j >= 4) && (j <= Lin - 4);
  for (int i = 0; i < Cin; ++i) {
    float xv[8];
    const float* xr = xb + (size_t)i * Lin + (j - 4);
    if (interior) {
#pragma unroll
      for (int k = 0; k < 8; ++k) xv[k] = xr[k];
    } else {
#pragma unroll
      for (int k = 0; k < 8; ++k) {
        int p = j + k - 4;
        xv[k] = (p >= 0 && p < Lin) ? xb[(size_t)i * Lin + p] : 0.f;
      }
    }
    const float* w0 = wr + i * 8;
#pragma unroll
    for (int k = 0; k < 8; ++k) {
      float xk = xv[k];
      a0 = fmaf(w0[k          ], xk, a0);
      a1 = fmaf(w0[k +     ws8], xk, a1);
      a2 = fmaf(w0[k + 2 * ws8], xk, a2);
      a3 = fmaf(w0[k + 3 * ws8], xk, a3);
    }
  }
  size_t base = ((size_t)b * Cout + o0) * Lc + j;
  y[base] = a0; y[base + Lc] = a1; y[base + 2 * (size_t)Lc] = a2; y[base + 3 * (size_t)Lc] = a3;
}

// BN batch stats per channel over (B, Lc); folds to A*x+B
__global__ void stats_k(const float* __restrict__ conv, const float* __restrict__ g,
                        const float* __restrict__ beta, float* __restrict__ bnA,
                        float* __restrict__ bnB, int C, int Lc) {
  int c = blockIdx.x;
  int n = BB * Lc;
  float s = 0.f, s2 = 0.f;
  for (int u = threadIdx.x; u < n; u += blockDim.x) {
    int b = u / Lc, j = u - b * Lc;
    float v = conv[((size_t)b * C + c) * Lc + j];
    s += v; s2 = fmaf(v, v, s2);
  }
#pragma unroll
  for (int off = 32; off; off >>= 1) { s += __shfl_down(s, off); s2 += __shfl_down(s2, off); }
  __shared__ float ps[4], ps2[4];
  if ((threadIdx.x & 63) == 0) { ps[threadIdx.x >> 6] = s; ps2[threadIdx.x >> 6] = s2; }
  __syncthreads();
  if (threadIdx.x == 0) {
    float S = ps[0] + ps[1] + ps[2] + ps[3];
    float S2 = ps2[0] + ps2[1] + ps2[2] + ps2[3];
    float mu = S / n;
    float var = S2 / n - mu * mu;
    float A = g[c] * rsqrtf(var + 1e-5f);
    bnA[c] = A;
    bnB[c] = beta[c] - mu * A;
  }
}

// BN-apply + ReLU + maxpool(2,2,pad1); writes pooled [B,C,T] and z [B,2T,C] (transposed via LDS)
__global__ void pool_k(const float* __restrict__ conv, const float* __restrict__ bnA,
                       const float* __restrict__ bnB, float* __restrict__ pooled,
                       float* __restrict__ zt, int C, int Lc, int Tout, int zoff) {
  __shared__ float tile[32][33];
  int b = blockIdx.z;
  int c0 = blockIdx.y * 32;
  int t0 = blockIdx.x * 32;
  int tx = threadIdx.x;  // 32
  int ty = threadIdx.y;  // 8
#pragma unroll
  for (int q = 0; q < 4; ++q) {
    int c = c0 + ty + q * 8;
    int t = t0 + tx;
    float v = 0.f;
    if (t < Tout) {
      const float* row = conv + ((size_t)b * C + c) * Lc;
      float A = bnA[c], Bb = bnB[c];
      v = -3.0e38f;
      int p0 = 2 * t - 1;
      if (p0 >= 0) v = fmaxf(v, fmaxf(fmaf(A, row[p0], Bb), 0.f));
      int p1 = 2 * t;
      if (p1 < Lc) v = fmaxf(v, fmaxf(fmaf(A, row[p1], Bb), 0.f));
      pooled[((size_t)b * C + c) * Tout + t] = v;
    }
    tile[ty + q * 8][tx] = v;
  }
  __syncthreads();
  int T2 = 2 * Tout;
#pragma unroll
  for (int q = 0; q < 4; ++q) {
    int t = t0 + ty + q * 8;
    int c = c0 + tx;
    if (t < Tout) zt[((size_t)b * T2 + zoff + t) * (size_t)C + c] = tile[tx][ty + q * 8];
  }
}

// timelag table (f64, thresholded like numpy) + row weight-sums
__global__ void ftab_k(float* __restrict__ ftab, float* __restrict__ roww, int T, float sigma) {
  __shared__ float fs[520];
  for (int d = threadIdx.x; d < T; d += blockDim.x) {
    double mm = 2.0 / (1.0 + exp((double)d * (double)sigma));
    float f = (mm < 1e-6) ? 0.f : (float)mm;
    ftab[d] = f; fs[d] = f;
  }
  __syncthreads();
  for (int i = threadIdx.x; i < T; i += blockDim.x) {
    float s = 0.f;
    for (int j = 0; j < T; ++j) { int d = i - j; d = d < 0 ? -d : d; s += fs[d]; }
    roww[i] = 2.f * s - fs[0];
  }
}

__device__ __forceinline__ void block_acc256(float v, double scale, double* acc) {
#pragma unroll
  for (int off = 32; off; off >>= 1) v += __shfl_down(v, off);
  __shared__ float part[4];
  if ((threadIdx.x & 63) == 0) part[threadIdx.x >> 6] = v;
  __syncthreads();
  if (threadIdx.x == 0)
    atomicAdd(acc, (double)(part[0] + part[1] + part[2] + part[3]) * scale);
}

// ---------- tiled temporal contrastive ----------
// grid (rowTiles, B), block 256. TM=16*MR rows/block, 64-col tiles via LDS.
template <int C, int MR>
__global__ void temp_loss2_k(const float* __restrict__ zt, const float* __restrict__ ftab,
                             const float* __restrict__ roww, int T, double scale, double* acc) {
  constexpr int TM = 16 * MR;
  constexpr int CP = C + 4;
  __shared__ float rowz[TM][CP];
  __shared__ float colz[64][CP];
  __shared__ float fsh[8];
  int tid = threadIdx.x;
  int b = blockIdx.y;
  int T2 = 2 * T;
  int i0 = blockIdx.x * TM;
  const float* zb = zt + (size_t)b * T2 * C;
  if (tid < 8) fsh[tid] = ftab[tid];
  for (int e = tid * 4; e < TM * C; e += 1024) {
    int r = e / C, k = e % C;
    int gr = i0 + r; gr = gr < T2 ? gr : T2 - 1;
    *(float4*)&rowz[r][k] = *(const float4*)(zb + (size_t)gr * C + k);
  }
  int l = tid & 15;
  int g = tid >> 4;
  int r0 = g * MR;
  int c0 = l * 4;
  float m[MR], se[MR];
  int ig[MR], ii[MR];
#pragma unroll
  for (int r = 0; r < MR; ++r) {
    m[r] = -3.0e38f; se[r] = 0.f;
    ig[r] = i0 + r0 + r;
    ii[r] = ig[r] < T ? ig[r] : ig[r] - T;
  }
  float wdot = 0.f;

  for (int j0 = 0; j0 < T2; j0 += 64) {
    __syncthreads();
    for (int e = tid * 4; e < 64 * C; e += 1024) {
      int r = e / C, k = e % C;
      int gr = j0 + r; gr = gr < T2 ? gr : T2 - 1;
      *(float4*)&colz[r][k] = *(const float4*)(zb + (size_t)gr * C + k);
    }
    __syncthreads();

    float dot[MR][4];
#pragma unroll
    for (int r = 0; r < MR; ++r)
#pragma unroll
      for (int q = 0; q < 4; ++q) dot[r][q] = 0.f;
#pragma unroll 4
    for (int k = 0; k < C; k += 4) {
      float4 av[MR], bv[4];
#pragma unroll
      for (int r = 0; r < MR; ++r) av[r] = *(const float4*)&rowz[r0 + r][k];
#pragma unroll
      for (int q = 0; q < 4; ++q) bv[q] = *(const float4*)&colz[c0 + q][k];
#pragma unroll
      for (int r = 0; r < MR; ++r)
#pragma unroll
        for (int q = 0; q < 4; ++q) {
          dot[r][q] = fmaf(av[r].x, bv[q].x, dot[r][q]);
          dot[r][q] = fmaf(av[r].y, bv[q].y, dot[r][q]);
          dot[r][q] = fmaf(av[r].z, bv[q].z, dot[r][q]);
          dot[r][q] = fmaf(av[r].w, bv[q].w, dot[r][q]);
        }
    }

#pragma unroll
    for (int r = 0; r < MR; ++r) {
      float sv[4]; bool vv[4];
      float tm = -3.0e38f;
#pragma unroll
      for (int q = 0; q < 4; ++q) {
        int jg = j0 + c0 + q;
        bool v = (jg < T2) && (jg != ig[r]) && (ig[r] < T2);
        float s = dot[r][q];
        int jj = jg < T ? jg : jg - T;
        int dd = ii[r] - jj; dd = dd < 0 ? -dd : dd;
        if (v && dd < 8) wdot = fmaf(fsh[dd], s, wdot);
        sv[q] = v ? s : -3.0e38f;
        vv[q] = v;
        tm = fmaxf(tm, sv[q]);
      }
#pragma unroll
      for (int off = 8; off; off >>= 1) tm = fmaxf(tm, __shfl_xor(tm, off));
      float p = 0.f;
#pragma unroll
      for (int q = 0; q < 4; ++q) p += vv[q] ? __expf(sv[q] - tm) : 0.f;
#pragma unroll
      for (int off = 8; off; off >>= 1) p += __shfl_xor(p, off);
      float mn = fmaxf(m[r], tm);
      se[r] = se[r] * __expf(m[r] - mn) + p * __expf(tm - mn);
      m[r] = mn;
    }
  }

  float tot = -wdot;
#pragma unroll
  for (int r = 0; r < MR; ++r) {
    if (l == 0 && ig[r] < T2) tot += roww[ii[r]] * (m[r] + __logf(se[r]));
  }
  block_acc256(tot, scale, acc);
}

// ---------- tiled instance contrastive ----------
// grid (128/TM, T), block 256. rows r in [0,128): b=r&63, half=(r<64).
template <int C, int MR>
__global__ void inst_loss2_k(const float* __restrict__ zt, const float* __restrict__ sl,
                             const float* __restrict__ slrs, int T, double scale, double* acc) {
  constexpr int TM = 16 * MR;
  constexpr int CP = C + 4;
  __shared__ float rowz[TM][CP];
  __shared__ float colz[64][CP];
  int tid = threadIdx.x;
  int t = blockIdx.y;
  int T2 = 2 * T;
  int i0 = blockIdx.x * TM;
  int l = tid & 15;
  int g = tid >> 4;
  int r0 = g * MR;
  int c0 = l * 4;

  for (int e = tid * 4; e < TM * C; e += 1024) {
    int r = e / C, k = e % C;
    int rr = i0 + r;
    size_t grow = (size_t)(rr & 63) * T2 + ((rr < 64) ? t : T + t);
    *(float4*)&rowz[r][k] = *(const float4*)(zt + grow * C + k);
  }

  int ig[MR]; float w[MR][4]; float rwv[MR];
#pragma unroll
  for (int r = 0; r < MR; ++r) {
    ig[r] = i0 + r0 + r;
    int bi = ig[r] & 63;
    rwv[r] = 2.f * slrs[bi] - sl[bi * 64 + bi];
#pragma unroll
    for (int q = 0; q < 4; ++q) w[r][q] = sl[bi * 64 + (c0 + q)];
  }
  float m[MR], se[MR];
#pragma unroll
  for (int r = 0; r < MR; ++r) { m[r] = -3.0e38f; se[r] = 0.f; }
  float wdot = 0.f;

  for (int j0 = 0; j0 < 128; j0 += 64) {
    __syncthreads();
    for (int e = tid * 4; e < 64 * C; e += 1024) {
      int r = e / C, k = e % C;
      int rr = j0 + r;
      size_t grow = (size_t)(rr & 63) * T2 + ((rr < 64) ? t : T + t);
      *(float4*)&colz[r][k] = *(const float4*)(zt + grow * C + k);
    }
    __syncthreads();

    float dot[MR][4];
#pragma unroll
    for (int r = 0; r < MR; ++r)
#pragma unroll
      for (int q = 0; q < 4; ++q) dot[r][q] = 0.f;
#pragma unroll 4
    for (int k = 0; k < C; k += 4) {
      float4 av[MR], bv[4];
#pragma unroll
      for (int r = 0; r < MR; ++r) av[r] = *(const float4*)&rowz[r0 + r][k];
#pragma unroll
      for (int q = 0; q < 4; ++q) bv[q] = *(const float4*)&colz[c0 + q][k];
#pragma unroll
      for (int r = 0; r < MR; ++r)
#pragma unroll
        for (int q = 0; q < 4; ++q) {
          dot[r][q] = fmaf(av[r].x, bv[q].x, dot[r][q]);
          dot[r][q] = fmaf(av[r].y, bv[q].y, dot[r][q]);
          dot[r][q] = fmaf(av[r].z, bv[q].z, dot[r][q]);
          dot[r][q] = fmaf(av[r].w, bv[q].w, dot[r][q]);
        }
    }

#pragma unroll
    for (int r = 0; r < MR; ++r) {
      float sv[4]; bool vv[4];
      float tm = -3.0e38f;
#pragma unroll
      for (int q = 0; q < 4; ++q) {
        int jg = j0 + c0 + q;
        bool v = (jg != ig[r]);
        float s = dot[r][q];
        if (v) wdot = fmaf(w[r][q], s, wdot);
        sv[q] = v ? s : -3.0e38f;
        vv[q] = v;
        tm = fmaxf(tm, sv[q]);
      }
#pragma unroll
      for (int off = 8; off; off >>= 1) tm = fmaxf(tm, __shfl_xor(tm, off));
      float p = 0.f;
#pragma unroll
      for (int q = 0; q < 4; ++q) p += vv[q] ? __expf(sv[q] - tm) : 0.f;
#pragma unroll
      for (int off = 8; off; off >>= 1) p += __shfl_xor(p, off);
      float mn = fmaxf(m[r], tm);
      se[r] = se[r] * __expf(m[r] - mn) + p * __expf(tm - mn);
      m[r] = mn;
    }
  }

  float tot = -wdot;
#pragma unroll
  for (int r = 0; r < MR; ++r) {
    if (l == 0) tot += rwv[r] * (m[r] + __logf(se[r]));
  }
  block_acc256(tot, scale, acc);
}

// final FC: lg[n,:] = a[n,:] @ wf + bf ; block per n
__global__ void fc_k(const float* __restrict__ a, const float* __restrict__ wf,
                     const float* __restrict__ bf, float* __restrict__ lg) {
  int n = blockIdx.x;
  float accv[5] = {0.f, 0.f, 0.f, 0.f, 0.f};
  for (int f = threadIdx.x; f < 16640; f += blockDim.x) {
    float av = a[(size_t)n * 16640 + f];
    const float* wr = wf + (size_t)f * 5;
#pragma unroll
    for (int k = 0; k < 5; ++k) accv[k] = fmaf(av, wr[k], accv[k]);
  }
  __shared__ float red[4][5];
#pragma unroll
  for (int k = 0; k < 5; ++k) {
    float v = accv[k];
#pragma unroll
    for (int off = 32; off; off >>= 1) v += __shfl_down(v, off);
    if ((threadIdx.x & 63) == 0) red[threadIdx.x >> 6][k] = v;
  }
  __syncthreads();
  if (threadIdx.x == 0) {
#pragma unroll
    for (int k = 0; k < 5; ++k) lg[n * 5 + k] = red[0][k] + red[1][k] + red[2][k] + red[3][k] + bf[k];
  }
}

__global__ void fin_k(const double* acc, float* out_loss) { *out_loss = (float)(*acc); }

extern "C" void kernel_launch(void* const* d_in, const int* in_sizes, int n_in,
                              void* d_out, int out_size, void* d_ws, size_t ws_size,
                              hipStream_t stream) {
  const float* aug[2] = {(const float*)d_in[0], (const float*)d_in[1]};
  const float* sl = (const float*)d_in[2];
  const float* wconv[3] = {(const float*)d_in[3], (const float*)d_in[6], (const float*)d_in[9]};
  const float* gam[3]   = {(const float*)d_in[4], (const float*)d_in[7], (const float*)d_in[10]};
  const float* bet[3]   = {(const float*)d_in[5], (const float*)d_in[8], (const float*)d_in[11]};
  const float* wf = (const float*)d_in[12];
  const float* bf = (const float*)d_in[13];
  float* out = (float*)d_out;
  float* ws = (float*)d_ws;
  if (ws_size < (size_t)WS_TOTAL * sizeof(float)) return;  // need ~34 MB scratch

  double* acc = (double*)ws;
  float* bnA = ws + WS_BNA;
  float* bnB = ws + WS_BNB;
  float* ftab = ws + WS_FTAB;
  float* roww = ws + WS_ROWW;
  float* slrs = ws + WS_SLRS;
  float* convb = ws + WS_CONV;
  float* zt = ws + WS_ZT;

  const int Cin[3]  = {1, 32, 64};
  const int Cout[3] = {32, 64, 128};
  const int Lin[3]  = {1024, 513, 258};
  const int Lc[3]   = {1025, 514, 259};
  const int Tarr[3] = {513, 258, 130};
  const float sig[3] = {2.f, 4.f, 8.f};

  float* A1 = out + O_A1;
  float* A2 = out + O_A2;

  init_k<<<1, 64, 0, stream>>>(acc, sl, slrs);

  for (int d = 0; d < 3; ++d) {
    int T = Tarr[d];
    for (int s = 0; s < 2; ++s) {
      const float* xin;
      float* pdst;
      if (d == 0)      { xin = aug[s];                               pdst = (s == 0) ? ws + WS_PA1 : ws + WS_PB1; }
      else if (d == 1) { xin = (s == 0) ? ws + WS_PA1 : ws + WS_PB1; pdst = (s == 0) ? ws + WS_PA2 : ws + WS_PB2; }
      else             { xin = (s == 0) ? ws + WS_PA2 : ws + WS_PB2; pdst = (s == 0) ? A1 : A2; }

      dim3 cg((Lc[d] + 255) / 256, BB * (Cout[d] / 4));
      conv_k<<<cg, 256, 0, stream>>>(xin, wconv[d], convb, Cin[d], Cout[d], Lin[d], Lc[d]);
      stats_k<<<Cout[d], 256, 0, stream>>>(convb, gam[d], bet[d], bnA, bnB, Cout[d], Lc[d]);
      dim3 pg((T + 31) / 32, Cout[d] / 32, BB);
      pool_k<<<pg, dim3(32, 8), 0, stream>>>(convb, bnA, bnB, pdst, zt, Cout[d], Lc[d], T, s * T);
    }
    ftab_k<<<1, 256, 0, stream>>>(ftab, roww, T, sig[d]);
    double scale = 0.5 / (128.0 * (double)T);  // (1-LAM)=LAM=0.5, /(2*B*T)
    int T2 = 2 * T;
    switch (d) {
      case 0:
        temp_loss2_k<32, 4><<<dim3((T2 + 63) / 64, BB), 256, 0, stream>>>(zt, ftab, roww, T, scale, acc);
        inst_loss2_k<32, 4><<<dim3(2, T), 256, 0, stream>>>(zt, sl, slrs, T, scale, acc);
        break;
      case 1:
        temp_loss2_k<64, 4><<<dim3((T2 + 63) / 64, BB), 256, 0, stream>>>(zt, ftab, roww, T, scale, acc);
        inst_loss2_k<64, 4><<<dim3(2, T), 256, 0, stream>>>(zt, sl, slrs, T, scale, acc);
        break;
      default:
        temp_loss2_k<128, 2><<<dim3((T2 + 31) / 32, BB), 256, 0, stream>>>(zt, ftab, roww, T, scale, acc);
        inst_loss2_k<128, 2><<<dim3(4, T), 256, 0, stream>>>(zt, sl, slrs, T, scale, acc);
        break;
    }
  }
  fc_k<<<64, 256, 0, stream>>>(A1, wf, bf, out + O_LG1);
  fc_k<<<64, 256, 0, stream>>>(A2, wf, bf, out + O_LG2);
  fin_k<<<1, 1, 0, stream>>>(acc, out + O_LOSS);
}

// Round 4
// 760.493 us; speedup vs baseline: 3.8950x; 1.6425x over previous
//
#include <hip/hip_runtime.h>
#include <hip/hip_bf16.h>
#include <math.h>

#define BB 64

typedef __attribute__((ext_vector_type(8))) short short8;
typedef __attribute__((ext_vector_type(4))) float f32x4;

// workspace layout (in floats)
#define WS_ACC   0
#define WS_BNA   4
#define WS_BNB   132
#define WS_FTAB  260
#define WS_ROWW  272
#define WS_SLRS  800
#define WS_CONV  896
#define SZ_CONV  2121728   // 64*128*259
#define SZ_PBUF  1056768   // 64*64*258 (max pooled intermediate)
#define WS_PA1   (WS_CONV + SZ_CONV)
#define WS_PA2   (WS_PA1 + SZ_PBUF)
#define WS_PB1   (WS_PA2 + SZ_PBUF)
#define WS_PB2   (WS_PB1 + SZ_PBUF)
#define WS_ZB16  (WS_PB2 + SZ_PBUF)
#define SZ_ZB16  1100000   // floats -> 2.2M bf16 >= 64*260*128
#define WS_TOTAL (WS_ZB16 + SZ_ZB16)

// d_out layout (floats)
#define O_LG1  0
#define O_LG2  320
#define O_A1   640
#define O_A2   (640 + 1064960)
#define O_LOSS (O_A2 + 1064960)

__global__ void init_k(double* acc, const float* __restrict__ sl, float* __restrict__ slrs) {
  if (threadIdx.x == 0) *acc = 0.0;
  int r = threadIdx.x;  // 64 threads
  float s = 0.f;
  for (int c = 0; c < 64; ++c) s += sl[r * 64 + c];
  slrs[r] = s;
}

// conv1d K=8 pad=4, 4 output channels per thread
__global__ void conv_k(const float* __restrict__ x, const float* __restrict__ w,
                       float* __restrict__ y, int Cin, int Cout, int Lin, int Lc) {
  int j = blockIdx.x * blockDim.x + threadIdx.x;
  if (j >= Lc) return;
  int nq = Cout >> 2;
  int oq = blockIdx.y % nq;
  int b  = blockIdx.y / nq;
  int o0 = oq << 2;
  const float* xb = x + (size_t)b * Cin * Lin;
  const float* wr = w + (size_t)o0 * Cin * 8;
  int ws8 = Cin * 8;
  float a0 = 0.f, a1 = 0.f, a2 = 0.f, a3 = 0.f;
  bool interior = (j >= 4) && (j <= Lin - 4);
  for (int i = 0; i < Cin; ++i) {
    float xv[8];
    const float* xr = xb + (size_t)i * Lin + (j - 4);
    if (interior) {
#pragma unroll
      for (int k = 0; k < 8; ++k) xv[k] = xr[k];
    } else {
#pragma unroll
      for (int k = 0; k < 8; ++k) {
        int p = j + k - 4;
        xv[k] = (p >= 0 && p < Lin) ? xb[(size_t)i * Lin + p] : 0.f;
      }
    }
    const float* w0 = wr + i * 8;
#pragma unroll
    for (int k = 0; k < 8; ++k) {
      float xk = xv[k];
      a0 = fmaf(w0[k          ], xk, a0);
      a1 = fmaf(w0[k +     ws8], xk, a1);
      a2 = fmaf(w0[k + 2 * ws8], xk, a2);
      a3 = fmaf(w0[k + 3 * ws8], xk, a3);
    }
  }
  size_t base = ((size_t)b * Cout + o0) * Lc + j;
  y[base] = a0; y[base + Lc] = a1; y[base + 2 * (size_t)Lc] = a2; y[base + 3 * (size_t)Lc] = a3;
}

// BN batch stats per channel over (B, Lc); folds to A*x+B. 1024 thr, no int div.
__global__ void stats_k(const float* __restrict__ conv, const float* __restrict__ g,
                        const float* __restrict__ beta, float* __restrict__ bnA,
                        float* __restrict__ bnB, int C, int Lc) {
  int c = blockIdx.x;
  float s = 0.f, s2 = 0.f;
  for (int b = 0; b < BB; ++b) {
    const float* row = conv + ((size_t)b * C + c) * Lc;
    for (int j = threadIdx.x; j < Lc; j += 1024) {
      float v = row[j];
      s += v; s2 = fmaf(v, v, s2);
    }
  }
#pragma unroll
  for (int off = 32; off; off >>= 1) { s += __shfl_down(s, off); s2 += __shfl_down(s2, off); }
  __shared__ float ps[16], ps2[16];
  if ((threadIdx.x & 63) == 0) { ps[threadIdx.x >> 6] = s; ps2[threadIdx.x >> 6] = s2; }
  __syncthreads();
  if (threadIdx.x == 0) {
    float S = 0.f, S2 = 0.f;
#pragma unroll
    for (int i = 0; i < 16; ++i) { S += ps[i]; S2 += ps2[i]; }
    float n = (float)(BB * Lc);
    float mu = S / n;
    float var = S2 / n - mu * mu;
    float A = g[c] * rsqrtf(var + 1e-5f);
    bnA[c] = A;
    bnB[c] = beta[c] - mu * A;
  }
}

// BN-apply + ReLU + maxpool(2,2,pad1); writes pooled fp32 [B,C,T] and z bf16 [B,2T,C]
__global__ void pool_k(const float* __restrict__ conv, const float* __restrict__ bnA,
                       const float* __restrict__ bnB, float* __restrict__ pooled,
                       __hip_bfloat16* __restrict__ zb, int C, int Lc, int Tout, int zoff) {
  __shared__ float tile[32][33];
  int b = blockIdx.z;
  int c0 = blockIdx.y * 32;
  int t0 = blockIdx.x * 32;
  int tx = threadIdx.x;  // 32
  int ty = threadIdx.y;  // 8
#pragma unroll
  for (int q = 0; q < 4; ++q) {
    int c = c0 + ty + q * 8;
    int t = t0 + tx;
    float v = 0.f;
    if (t < Tout) {
      const float* row = conv + ((size_t)b * C + c) * Lc;
      float A = bnA[c], Bb = bnB[c];
      v = -3.0e38f;
      int p0 = 2 * t - 1;
      if (p0 >= 0) v = fmaxf(v, fmaxf(fmaf(A, row[p0], Bb), 0.f));
      int p1 = 2 * t;
      if (p1 < Lc) v = fmaxf(v, fmaxf(fmaf(A, row[p1], Bb), 0.f));
      pooled[((size_t)b * C + c) * Tout + t] = v;
    }
    tile[ty + q * 8][tx] = v;
  }
  __syncthreads();
  int T2 = 2 * Tout;
#pragma unroll
  for (int q = 0; q < 4; ++q) {
    int t = t0 + ty + q * 8;
    int c = c0 + tx;
    if (t < Tout)
      zb[((size_t)b * T2 + zoff + t) * (size_t)C + c] = __float2bfloat16(tile[tx][ty + q * 8]);
  }
}

// timelag f(d) for d<8 (f64 thresholded like numpy; 0 beyond 7 for all sigmas) + closed-form row sums
__global__ void ftab_k(float* __restrict__ ftab, float* __restrict__ roww, int T, float sigma) {
  __shared__ float fs[8];
  if (threadIdx.x < 8) {
    double mm = 2.0 / (1.0 + exp((double)threadIdx.x * (double)sigma));
    float f = (mm < 1e-6) ? 0.f : (float)mm;
    ftab[threadIdx.x] = f; fs[threadIdx.x] = f;
  }
  __syncthreads();
  for (int i = threadIdx.x; i < T; i += blockDim.x) {
    float s = fs[0];
#pragma unroll
    for (int d = 1; d < 8; ++d) s += fs[d] * ((i >= d ? 1.f : 0.f) + (i + d < T ? 1.f : 0.f));
    roww[i] = 2.f * s - fs[0];
  }
}

__device__ __forceinline__ void block_acc256(float v, double scale, double* acc) {
#pragma unroll
  for (int off = 32; off; off >>= 1) v += __shfl_down(v, off);
  __shared__ float part[4];
  if ((threadIdx.x & 63) == 0) part[threadIdx.x >> 6] = v;
  __syncthreads();
  if (threadIdx.x == 0)
    atomicAdd(acc, (double)(part[0] + part[1] + part[2] + part[3]) * scale);
}

// ---------- MFMA temporal contrastive (rw*lse part; wdot handled by band_k) ----------
// grid (ceil(2T/64), B), 256 thr = 4 waves x 16 rows. Two passes: max, then expsum.
template <int C, int NC>
__launch_bounds__(256)
__global__ void temp_mfma_k(const __hip_bfloat16* __restrict__ zb,
                            const float* __restrict__ roww,
                            int T, double scale, double* __restrict__ acc) {
  constexpr int KST = C / 32;
  constexpr int STR = 2 * C + 16;   // padded LDS row stride (bytes): 2-way conflicts max
  constexpr int CH8 = C / 8;        // 16B chunks per row
  __shared__ float4 colz4[NC * STR / 16];
  char* colz = (char*)colz4;
  const int tid = threadIdx.x;
  const int wave = tid >> 6, lane = tid & 63, l15 = lane & 15, l4 = lane >> 4;
  const int b = blockIdx.y;
  const int T2 = 2 * T;
  const int T2pad = ((T2 + 15) >> 4) << 4;
  const int i0 = blockIdx.x * 64 + wave * 16;
  const __hip_bfloat16* zbb = zb + (size_t)b * T2 * C;

  short8 af[KST];
  {
    int ar = i0 + l15; if (ar > T2 - 1) ar = T2 - 1;
#pragma unroll
    for (int ks = 0; ks < KST; ++ks)
      af[ks] = *(const short8*)(zbb + (size_t)ar * C + ks * 32 + l4 * 8);
  }
  float M[4], se[4];
#pragma unroll
  for (int r = 0; r < 4; ++r) { M[r] = -3.0e38f; se[r] = 0.f; }

  const bool multi = (T2pad > NC);
  for (int pass = 0; pass < 2; ++pass) {
    if (pass) {
#pragma unroll
      for (int r = 0; r < 4; ++r)
#pragma unroll
        for (int off = 1; off < 16; off <<= 1)
          M[r] = fmaxf(M[r], __shfl_xor(M[r], off));
    }
    for (int cb = 0; cb < T2pad; cb += NC) {
      int rowsHere = T2pad - cb; if (rowsHere > NC) rowsHere = NC;
      if (pass == 0 || multi) {
        __syncthreads();
        for (int idx = tid; idx < rowsHere * CH8; idx += 256) {
          int jr = idx / CH8, s = idx - jr * CH8;
          int gr = cb + jr; if (gr > T2 - 1) gr = T2 - 1;
          *(float4*)(colz + jr * STR + s * 16) = *(const float4*)(zbb + (size_t)gr * C + s * 8);
        }
        __syncthreads();
      }
      int ntiles = rowsHere >> 4;
      for (int ct = 0; ct < ntiles; ++ct) {
        int cj0 = cb + ct * 16;
        f32x4 d = {0.f, 0.f, 0.f, 0.f};
#pragma unroll
        for (int ks = 0; ks < KST; ++ks) {
          short8 bv = *(const short8*)(colz + (ct * 16 + l15) * STR + ks * 64 + l4 * 16);
          d = __builtin_amdgcn_mfma_f32_16x16x32_bf16(af[ks], bv, d, 0, 0, 0);
        }
        bool special = (cj0 == i0) || (cj0 + 16 > T2);
        int jg = cj0 + l15;
        if (pass == 0) {
          if (special) {
#pragma unroll
            for (int r = 0; r < 4; ++r) {
              int ig = i0 + l4 * 4 + r;
              if (jg < T2 && jg != ig) M[r] = fmaxf(M[r], d[r]);
            }
          } else {
#pragma unroll
            for (int r = 0; r < 4; ++r) M[r] = fmaxf(M[r], d[r]);
          }
        } else {
          if (special) {
#pragma unroll
            for (int r = 0; r < 4; ++r) {
              int ig = i0 + l4 * 4 + r;
              se[r] += (jg < T2 && jg != ig) ? __expf(d[r] - M[r]) : 0.f;
            }
          } else {
#pragma unroll
            for (int r = 0; r < 4; ++r) se[r] += __expf(d[r] - M[r]);
          }
        }
      }
    }
  }
  float tot = 0.f;
#pragma unroll
  for (int r = 0; r < 4; ++r) {
#pragma unroll
    for (int off = 1; off < 16; off <<= 1) se[r] += __shfl_xor(se[r], off);
    int ig = i0 + l4 * 4 + r;
    if (l15 == 0 && ig < T2) {
      int ii = ig < T ? ig : ig - T;
      tot += roww[ii] * (M[r] + __logf(se[r]));
    }
  }
  block_acc256(tot, scale, acc);
}

// ---------- band wdot for temporal loss: sum f(|ii-jj|) * y_ii . y_jj  - f0*sum norms ----------
// y = z1+z2 per (b,ii). grid (ceil(T/64), B), 256 thr.
template <int C>
__launch_bounds__(256)
__global__ void band_k(const __hip_bfloat16* __restrict__ zb, const float* __restrict__ ftab,
                       int T, double scale, double* __restrict__ acc) {
  __shared__ float y[78][C + 1];
  __shared__ float f[8];
  const int tid = threadIdx.x;
  const int b = blockIdx.y, ii0 = blockIdx.x * 64;
  const int T2 = 2 * T;
  if (tid < 8) f[tid] = ftab[tid];
  const __hip_bfloat16* zbb = zb + (size_t)b * T2 * C;
  for (int idx = tid; idx < 78 * C; idx += 256) {
    int rr = idx / C, k = idx - rr * C;
    int ii = ii0 - 7 + rr;
    float v = 0.f;
    if (ii >= 0 && ii < T)
      v = __bfloat162float(zbb[(size_t)ii * C + k]) +
          __bfloat162float(zbb[(size_t)(T + ii) * C + k]);
    y[rr][k] = v;
  }
  float p2 = 0.f;
  for (int idx = tid; idx < 64 * C; idx += 256) {
    int rr = idx / C, k = idx - rr * C;
    int ii = ii0 + rr;
    if (ii < T) {
      float v1 = __bfloat162float(zbb[(size_t)ii * C + k]);
      float v2 = __bfloat162float(zbb[(size_t)(T + ii) * C + k]);
      p2 = fmaf(v1, v1, p2); p2 = fmaf(v2, v2, p2);
    }
  }
  __syncthreads();
  const int m = tid & 63, q = tid >> 6;
  float p = 0.f;
  if (ii0 + m < T) {
    int rr = m + 7;
    constexpr int SL = C / 4;
    for (int k = q * SL; k < (q + 1) * SL; ++k) {
      float g = f[0] * y[rr][k];
#pragma unroll
      for (int dd = 1; dd < 8; ++dd) g = fmaf(f[dd], y[rr - dd][k] + y[rr + dd][k], g);
      p = fmaf(y[rr][k], g, p);
    }
  }
  block_acc256(f[0] * p2 - p, scale, acc);
}

// ---------- MFMA instance contrastive ----------
// grid (T), 256 thr = 4 waves x 32 rows (2 row-tiles each); 128x128 sim per t.
template <int C>
__launch_bounds__(256)
__global__ void inst_mfma_k(const __hip_bfloat16* __restrict__ zb,
                            const float* __restrict__ sl,
                            const float* __restrict__ slrs,
                            int T, double scale, double* __restrict__ acc) {
  constexpr int KST = C / 32;
  constexpr int STR = 2 * C + 16;
  constexpr int CH8 = C / 8;
  __shared__ float4 rz4[128 * STR / 16];
  __shared__ float ssh[64][65];
  char* rz = (char*)rz4;
  const int tid = threadIdx.x;
  const int wave = tid >> 6, lane = tid & 63, l15 = lane & 15, l4 = lane >> 4;
  const int t = blockIdx.x;
  const int T2 = 2 * T;
  for (int idx = tid; idx < 128 * CH8; idx += 256) {
    int r = idx / CH8, s = idx - r * CH8;
    size_t grow = (size_t)(r & 63) * T2 + ((r < 64) ? t : T + t);
    *(float4*)(rz + r * STR + s * 16) = *(const float4*)(zb + grow * C + s * 8);
  }
  for (int u = tid; u < 4096; u += 256) ssh[u >> 6][u & 63] = sl[u];
  __syncthreads();

  short8 af[2][KST];
#pragma unroll
  for (int rt = 0; rt < 2; ++rt) {
    int row = wave * 32 + rt * 16 + l15;
#pragma unroll
    for (int ks = 0; ks < KST; ++ks)
      af[rt][ks] = *(const short8*)(rz + row * STR + ks * 64 + l4 * 16);
  }
  float M[2][4], se[2][4];
#pragma unroll
  for (int rt = 0; rt < 2; ++rt)
#pragma unroll
    for (int r = 0; r < 4; ++r) { M[rt][r] = -3.0e38f; se[rt][r] = 0.f; }
  float wdot = 0.f;

  for (int pass = 0; pass < 2; ++pass) {
    if (pass) {
#pragma unroll
      for (int rt = 0; rt < 2; ++rt)
#pragma unroll
        for (int r = 0; r < 4; ++r)
#pragma unroll
          for (int off = 1; off < 16; off <<= 1)
            M[rt][r] = fmaxf(M[rt][r], __shfl_xor(M[rt][r], off));
    }
#pragma unroll
    for (int rt = 0; rt < 2; ++rt) {
      int ri0 = wave * 32 + rt * 16;
      for (int ct = 0; ct < 8; ++ct) {
        int cj0 = ct * 16;
        f32x4 d = {0.f, 0.f, 0.f, 0.f};
#pragma unroll
        for (int ks = 0; ks < KST; ++ks) {
          short8 bv = *(const short8*)(rz + (cj0 + l15) * STR + ks * 64 + l4 * 16);
          d = __builtin_amdgcn_mfma_f32_16x16x32_bf16(af[rt][ks], bv, d, 0, 0, 0);
        }
        bool diag = (ri0 == cj0);
        int jg = cj0 + l15;
        if (pass == 0) {
#pragma unroll
          for (int r = 0; r < 4; ++r) {
            int ig = ri0 + l4 * 4 + r;
            if (!diag || jg != ig) M[rt][r] = fmaxf(M[rt][r], d[r]);
          }
        } else {
          int bj = jg & 63;
#pragma unroll
          for (int r = 0; r < 4; ++r) {
            int ig = ri0 + l4 * 4 + r;
            bool v = (!diag || jg != ig);
            se[rt][r] += v ? __expf(d[r] - M[rt][r]) : 0.f;
            wdot += v ? ssh[ig & 63][bj] * d[r] : 0.f;
          }
        }
      }
    }
  }
  float tot = -wdot;
#pragma unroll
  for (int rt = 0; rt < 2; ++rt)
#pragma unroll
    for (int r = 0; r < 4; ++r) {
#pragma unroll
      for (int off = 1; off < 16; off <<= 1) se[rt][r] += __shfl_xor(se[rt][r], off);
      if (l15 == 0) {
        int ig = wave * 32 + rt * 16 + l4 * 4 + r;
        int bi = ig & 63;
        float rw = 2.f * slrs[bi] - ssh[bi][bi];
        tot += rw * (M[rt][r] + __logf(se[rt][r]));
      }
    }
  block_acc256(tot, scale, acc);
}

// final FC: lg[n,:] = a[n,:] @ wf + bf ; block per n, 1024 thr
__global__ void fc_k(const float* __restrict__ a, const float* __restrict__ wf,
                     const float* __restrict__ bf, float* __restrict__ lg) {
  int n = blockIdx.x;
  float accv[5] = {0.f, 0.f, 0.f, 0.f, 0.f};
  for (int f = threadIdx.x; f < 16640; f += 1024) {
    float av = a[(size_t)n * 16640 + f];
    const float* wr = wf + (size_t)f * 5;
#pragma unroll
    for (int k = 0; k < 5; ++k) accv[k] = fmaf(av, wr[k], accv[k]);
  }
  __shared__ float red[16][5];
#pragma unroll
  for (int k = 0; k < 5; ++k) {
    float v = accv[k];
#pragma unroll
    for (int off = 32; off; off >>= 1) v += __shfl_down(v, off);
    if ((threadIdx.x & 63) == 0) red[threadIdx.x >> 6][k] = v;
  }
  __syncthreads();
  if (threadIdx.x == 0) {
#pragma unroll
    for (int k = 0; k < 5; ++k) {
      float s = bf[k];
#pragma unroll
      for (int i = 0; i < 16; ++i) s += red[i][k];
      lg[n * 5 + k] = s;
    }
  }
}

__global__ void fin_k(const double* acc, float* out_loss) { *out_loss = (float)(*acc); }

extern "C" void kernel_launch(void* const* d_in, const int* in_sizes, int n_in,
                              void* d_out, int out_size, void* d_ws, size_t ws_size,
                              hipStream_t stream) {
  const float* aug[2] = {(const float*)d_in[0], (const float*)d_in[1]};
  const float* sl = (const float*)d_in[2];
  const float* wconv[3] = {(const float*)d_in[3], (const float*)d_in[6], (const float*)d_in[9]};
  const float* gam[3]   = {(const float*)d_in[4], (const float*)d_in[7], (const float*)d_in[10]};
  const float* bet[3]   = {(const float*)d_in[5], (const float*)d_in[8], (const float*)d_in[11]};
  const float* wf = (const float*)d_in[12];
  const float* bf = (const float*)d_in[13];
  float* out = (float*)d_out;
  float* ws = (float*)d_ws;
  if (ws_size < (size_t)WS_TOTAL * sizeof(float)) return;  // need ~30 MB scratch

  double* acc = (double*)(ws + WS_ACC);
  float* bnA = ws + WS_BNA;
  float* bnB = ws + WS_BNB;
  float* ftab = ws + WS_FTAB;
  float* roww = ws + WS_ROWW;
  float* slrs = ws + WS_SLRS;
  float* convb = ws + WS_CONV;
  __hip_bfloat16* zb16 = (__hip_bfloat16*)(ws + WS_ZB16);

  const int Cin[3]  = {1, 32, 64};
  const int Cout[3] = {32, 64, 128};
  const int Lin[3]  = {1024, 513, 258};
  const int Lc[3]   = {1025, 514, 259};
  const int Tarr[3] = {513, 258, 130};
  const float sig[3] = {2.f, 4.f, 8.f};

  float* A1 = out + O_A1;
  float* A2 = out + O_A2;

  init_k<<<1, 64, 0, stream>>>(acc, sl, slrs);

  for (int d = 0; d < 3; ++d) {
    int T = Tarr[d];
    int T2 = 2 * T;
    for (int s = 0; s < 2; ++s) {
      const float* xin;
      float* pdst;
      if (d == 0)      { xin = aug[s];                               pdst = (s == 0) ? ws + WS_PA1 : ws + WS_PB1; }
      else if (d == 1) { xin = (s == 0) ? ws + WS_PA1 : ws + WS_PB1; pdst = (s == 0) ? ws + WS_PA2 : ws + WS_PB2; }
      else             { xin = (s == 0) ? ws + WS_PA2 : ws + WS_PB2; pdst = (s == 0) ? A1 : A2; }

      dim3 cg((Lc[d] + 255) / 256, BB * (Cout[d] / 4));
      conv_k<<<cg, 256, 0, stream>>>(xin, wconv[d], convb, Cin[d], Cout[d], Lin[d], Lc[d]);
      stats_k<<<Cout[d], 1024, 0, stream>>>(convb, gam[d], bet[d], bnA, bnB, Cout[d], Lc[d]);
      dim3 pg((T + 31) / 32, Cout[d] / 32, BB);
      pool_k<<<pg, dim3(32, 8), 0, stream>>>(convb, bnA, bnB, pdst, zb16, Cout[d], Lc[d], T, s * T);
    }
    ftab_k<<<1, 256, 0, stream>>>(ftab, roww, T, sig[d]);
    double scale = 0.5 / (128.0 * (double)T);  // (1-LAM)=LAM=0.5, /(2*B*T)
    dim3 tg((T2 + 63) / 64, BB);
    dim3 bg((T + 63) / 64, BB);
    switch (d) {
      case 0:
        temp_mfma_k<32, 512><<<tg, 256, 0, stream>>>(zb16, roww, T, scale, acc);
        band_k<32><<<bg, 256, 0, stream>>>(zb16, ftab, T, scale, acc);
        inst_mfma_k<32><<<T, 256, 0, stream>>>(zb16, sl, slrs, T, scale, acc);
        break;
      case 1:
        temp_mfma_k<64, 256><<<tg, 256, 0, stream>>>(zb16, roww, T, scale, acc);
        band_k<64><<<bg, 256, 0, stream>>>(zb16, ftab, T, scale, acc);
        inst_mfma_k<64><<<T, 256, 0, stream>>>(zb16, sl, slrs, T, scale, acc);
        break;
      default:
        temp_mfma_k<128, 128><<<tg, 256, 0, stream>>>(zb16, roww, T, scale, acc);
        band_k<128><<<bg, 256, 0, stream>>>(zb16, ftab, T, scale, acc);
        inst_mfma_k<128><<<T, 256, 0, stream>>>(zb16, sl, slrs, T, scale, acc);
        break;
    }
  }
  fc_k<<<64, 1024, 0, stream>>>(A1, wf, bf, out + O_LG1);
  fc_k<<<64, 1024, 0, stream>>>(A2, wf, bf, out + O_LG2);
  fin_k<<<1, 1, 0, stream>>>(acc, out + O_LOSS);
}

// Round 5
// 432.822 us; speedup vs baseline: 6.8437x; 1.7571x over previous
//
#include <hip/hip_runtime.h>
#include <hip/hip_bf16.h>
#include <math.h>

#define BB 64
#define PB_STRIDE 1536

typedef __attribute__((ext_vector_type(8))) short short8;
typedef __attribute__((ext_vector_type(4))) float f32x4;

// workspace layout (in floats)
#define WS_ACC   0
#define WS_BNA   4
#define WS_BNB   132
#define WS_FTAB  260
#define WS_ROWW  272
#define WS_SLRS  800
#define WS_WBF1  896      // 512 floats  (1024 bf16)
#define WS_WBF2  1408     // 8192 floats (16384 bf16)
#define WS_WBF3  9600     // 32768 floats (65536 bf16)
#define WS_PART1 42368    // 196608
#define WS_PART2 238976   // 196608
#define WS_CONV  435584
#define SZ_CONV  2121728  // 64*128*259
#define SZ_PBUF  1056768  // 64*64*258
#define WS_PA1   (WS_CONV + SZ_CONV)
#define WS_PA2   (WS_PA1 + SZ_PBUF)
#define WS_PB1   (WS_PA2 + SZ_PBUF)
#define WS_PB2   (WS_PB1 + SZ_PBUF)
#define WS_ZB16  (WS_PB2 + SZ_PBUF)
#define SZ_ZB16  1100000  // floats -> 2.2M bf16 >= 64*260*128
#define WS_TOTAL (WS_ZB16 + SZ_ZB16)

// d_out layout (floats)
#define O_LG1  0
#define O_LG2  320
#define O_A1   640
#define O_A2   (640 + 1064960)
#define O_LOSS (O_A2 + 1064960)

__device__ __forceinline__ short f2bf(float f) {
  unsigned u = __float_as_uint(f);
  u += 0x7FFFu + ((u >> 16) & 1u);
  return (short)(u >> 16);
}

__global__ void init_k(double* acc, const float* __restrict__ sl, float* __restrict__ slrs) {
  if (threadIdx.x == 0) *acc = 0.0;
  int r = threadIdx.x;  // 64 threads
  float s = 0.f;
  for (int c = 0; c < 64; ++c) s += sl[r * 64 + c];
  slrs[r] = s;
}

// fp32 w [O][CIN*8] -> bf16 [O][KTOT] (zero-padded K)
__global__ void wprep_k(const float* __restrict__ w, short* __restrict__ wbf,
                        int nreal, int KTOT, int total) {
  int i = blockIdx.x * 256 + threadIdx.x;
  if (i >= total) return;
  int o = i / KTOT, q = i - o * KTOT;
  short v = 0;
  if (q < nreal) v = f2bf(w[o * nreal + q]);
  wbf[i] = v;
}

// ---------- implicit-GEMM MFMA conv1d (K=8, pad=4) + fused BN partial stats ----------
// block: one b, 64 j, all COUT. 4 waves, each 16 j x COUT.
template <int CIN, int COUT, int CHUNK_CI>
__launch_bounds__(256)
__global__ void conv_mfma_k(const float* __restrict__ x, const short* __restrict__ wbf,
                            float* __restrict__ y, float* __restrict__ part_s,
                            float* __restrict__ part_s2, int Lin, int Lc) {
  constexpr int CIPAD = (CIN < 4) ? 4 : CIN;
  constexpr int KTOT = CIPAD * 8;
  constexpr int NCHUNK = CIPAD / CHUNK_CI;
  constexpr int ROWS8 = CHUNK_CI + 1;   // short8 per LDS row (+16B pad)
  constexpr int NT = COUT / 16;
  __shared__ short8 a8[64 * ROWS8];
  __shared__ float ps[4][COUT], ps2[4][COUT];
  short* a_lds = (short*)a8;
  const int tid = threadIdx.x;
  const int wave = tid >> 6, lane = tid & 63, l15 = lane & 15, l4 = lane >> 4;
  const int b = blockIdx.y;
  const int j0 = blockIdx.x * 64;
  const float* xb = x + (size_t)b * CIN * Lin;

  f32x4 acc[NT];
#pragma unroll
  for (int nt = 0; nt < NT; ++nt) acc[nt] = (f32x4){0.f, 0.f, 0.f, 0.f};

  for (int ch = 0; ch < NCHUNK; ++ch) {
    __syncthreads();
    for (int idx = tid; idx < 64 * CHUNK_CI; idx += 256) {
      int jr = idx & 63;
      int cc = idx >> 6;
      int ci = ch * CHUNK_CI + cc;
      short8 sv = (short8){0, 0, 0, 0, 0, 0, 0, 0};
      if (ci < CIN) {
        const float* xr = xb + (size_t)ci * Lin;
        int p0 = j0 + jr - 4;
#pragma unroll
        for (int k = 0; k < 8; ++k) {
          int p = p0 + k;
          float v = (p >= 0 && p < Lin) ? xr[p] : 0.f;
          sv[k] = f2bf(v);
        }
      }
      *(short8*)(a_lds + jr * (ROWS8 * 8) + cc * 8) = sv;
    }
    __syncthreads();
#pragma unroll
    for (int ks = 0; ks < CHUNK_CI / 4; ++ks) {
      short8 af = *(const short8*)(a_lds + (wave * 16 + l15) * (ROWS8 * 8) + ks * 32 + l4 * 8);
      const short* wrow = wbf + (size_t)l15 * KTOT + (ch * CHUNK_CI * 8 + ks * 32 + l4 * 8);
#pragma unroll
      for (int nt = 0; nt < NT; ++nt) {
        short8 bv = *(const short8*)(wrow + (size_t)nt * 16 * KTOT);
        acc[nt] = __builtin_amdgcn_mfma_f32_16x16x32_bf16(af, bv, acc[nt], 0, 0, 0);
      }
    }
  }

  // epilogue: store + per-channel partial stats
  const int jbase = j0 + wave * 16 + l4 * 4;
#pragma unroll
  for (int nt = 0; nt < NT; ++nt) {
    int o = nt * 16 + l15;
    float* yr = y + ((size_t)b * COUT + o) * Lc;
    float s = 0.f, s2 = 0.f;
    if (jbase + 3 < Lc) {
      *(float4*)(yr + jbase) = (float4){acc[nt][0], acc[nt][1], acc[nt][2], acc[nt][3]};
#pragma unroll
      for (int r = 0; r < 4; ++r) { float v = acc[nt][r]; s += v; s2 = fmaf(v, v, s2); }
    } else {
#pragma unroll
      for (int r = 0; r < 4; ++r) {
        if (jbase + r < Lc) { float v = acc[nt][r]; yr[jbase + r] = v; s += v; s2 = fmaf(v, v, s2); }
      }
    }
    s  += __shfl_xor(s, 16);  s  += __shfl_xor(s, 32);
    s2 += __shfl_xor(s2, 16); s2 += __shfl_xor(s2, 32);
    if (lane < 16) { ps[wave][nt * 16 + lane] = s; ps2[wave][nt * 16 + lane] = s2; }
  }
  __syncthreads();
  int blk = blockIdx.y * gridDim.x + blockIdx.x;
  for (int o = tid; o < COUT; o += 256) {
    part_s [o * PB_STRIDE + blk] = ps[0][o] + ps[1][o] + ps[2][o] + ps[3][o];
    part_s2[o * PB_STRIDE + blk] = ps2[0][o] + ps2[1][o] + ps2[2][o] + ps2[3][o];
  }
}

// reduce conv partials -> bnA/bnB (deterministic)
__global__ void stats2_k(const float* __restrict__ part_s, const float* __restrict__ part_s2,
                         const float* __restrict__ g, const float* __restrict__ beta,
                         float* __restrict__ bnA, float* __restrict__ bnB, int nblk, int n) {
  int c = blockIdx.x;
  float s = 0.f, s2 = 0.f;
  for (int i = threadIdx.x; i < nblk; i += 256) {
    s += part_s[c * PB_STRIDE + i];
    s2 += part_s2[c * PB_STRIDE + i];
  }
#pragma unroll
  for (int off = 32; off; off >>= 1) { s += __shfl_down(s, off); s2 += __shfl_down(s2, off); }
  __shared__ float as[4], as2[4];
  if ((threadIdx.x & 63) == 0) { as[threadIdx.x >> 6] = s; as2[threadIdx.x >> 6] = s2; }
  __syncthreads();
  if (threadIdx.x == 0) {
    float S = as[0] + as[1] + as[2] + as[3];
    float S2 = as2[0] + as2[1] + as2[2] + as2[3];
    float fn = (float)n;
    float mu = S / fn;
    float var = S2 / fn - mu * mu;
    float A = g[c] * rsqrtf(var + 1e-5f);
    bnA[c] = A;
    bnB[c] = beta[c] - mu * A;
  }
}

// BN-apply + ReLU + maxpool(2,2,pad1); writes pooled fp32 [B,C,T] and z bf16 [B,2T,C]
__global__ void pool_k(const float* __restrict__ conv, const float* __restrict__ bnA,
                       const float* __restrict__ bnB, float* __restrict__ pooled,
                       __hip_bfloat16* __restrict__ zb, int C, int Lc, int Tout, int zoff) {
  __shared__ float tile[32][33];
  int b = blockIdx.z;
  int c0 = blockIdx.y * 32;
  int t0 = blockIdx.x * 32;
  int tx = threadIdx.x;  // 32
  int ty = threadIdx.y;  // 8
#pragma unroll
  for (int q = 0; q < 4; ++q) {
    int c = c0 + ty + q * 8;
    int t = t0 + tx;
    float v = 0.f;
    if (t < Tout) {
      const float* row = conv + ((size_t)b * C + c) * Lc;
      float A = bnA[c], Bb = bnB[c];
      v = -3.0e38f;
      int p0 = 2 * t - 1;
      if (p0 >= 0) v = fmaxf(v, fmaxf(fmaf(A, row[p0], Bb), 0.f));
      int p1 = 2 * t;
      if (p1 < Lc) v = fmaxf(v, fmaxf(fmaf(A, row[p1], Bb), 0.f));
      pooled[((size_t)b * C + c) * Tout + t] = v;
    }
    tile[ty + q * 8][tx] = v;
  }
  __syncthreads();
  int T2 = 2 * Tout;
#pragma unroll
  for (int q = 0; q < 4; ++q) {
    int t = t0 + ty + q * 8;
    int c = c0 + tx;
    if (t < Tout)
      zb[((size_t)b * T2 + zoff + t) * (size_t)C + c] = __float2bfloat16(tile[tx][ty + q * 8]);
  }
}

// timelag f(d) for d<8 + closed-form row sums
__global__ void ftab_k(float* __restrict__ ftab, float* __restrict__ roww, int T, float sigma) {
  __shared__ float fs[8];
  if (threadIdx.x < 8) {
    double mm = 2.0 / (1.0 + exp((double)threadIdx.x * (double)sigma));
    float f = (mm < 1e-6) ? 0.f : (float)mm;
    ftab[threadIdx.x] = f; fs[threadIdx.x] = f;
  }
  __syncthreads();
  for (int i = threadIdx.x; i < T; i += blockDim.x) {
    float s = fs[0];
#pragma unroll
    for (int d = 1; d < 8; ++d) s += fs[d] * ((i >= d ? 1.f : 0.f) + (i + d < T ? 1.f : 0.f));
    roww[i] = 2.f * s - fs[0];
  }
}

__device__ __forceinline__ void block_acc256(float v, double scale, double* acc) {
#pragma unroll
  for (int off = 32; off; off >>= 1) v += __shfl_down(v, off);
  __shared__ float part[4];
  if ((threadIdx.x & 63) == 0) part[threadIdx.x >> 6] = v;
  __syncthreads();
  if (threadIdx.x == 0)
    atomicAdd(acc, (double)(part[0] + part[1] + part[2] + part[3]) * scale);
}

// ---------- MFMA temporal contrastive ----------
template <int C, int NC>
__launch_bounds__(256)
__global__ void temp_mfma_k(const __hip_bfloat16* __restrict__ zb,
                            const float* __restrict__ roww,
                            int T, double scale, double* __restrict__ acc) {
  constexpr int KST = C / 32;
  constexpr int STR = 2 * C + 16;
  constexpr int CH8 = C / 8;
  __shared__ float4 colz4[NC * STR / 16];
  char* colz = (char*)colz4;
  const int tid = threadIdx.x;
  const int wave = tid >> 6, lane = tid & 63, l15 = lane & 15, l4 = lane >> 4;
  const int b = blockIdx.y;
  const int T2 = 2 * T;
  const int T2pad = ((T2 + 15) >> 4) << 4;
  const int i0 = blockIdx.x * 64 + wave * 16;
  const __hip_bfloat16* zbb = zb + (size_t)b * T2 * C;

  short8 af[KST];
  {
    int ar = i0 + l15; if (ar > T2 - 1) ar = T2 - 1;
#pragma unroll
    for (int ks = 0; ks < KST; ++ks)
      af[ks] = *(const short8*)(zbb + (size_t)ar * C + ks * 32 + l4 * 8);
  }
  float M[4], se[4];
#pragma unroll
  for (int r = 0; r < 4; ++r) { M[r] = -3.0e38f; se[r] = 0.f; }

  const bool multi = (T2pad > NC);
  for (int pass = 0; pass < 2; ++pass) {
    if (pass) {
#pragma unroll
      for (int r = 0; r < 4; ++r)
#pragma unroll
        for (int off = 1; off < 16; off <<= 1)
          M[r] = fmaxf(M[r], __shfl_xor(M[r], off));
    }
    for (int cb = 0; cb < T2pad; cb += NC) {
      int rowsHere = T2pad - cb; if (rowsHere > NC) rowsHere = NC;
      if (pass == 0 || multi) {
        __syncthreads();
        for (int idx = tid; idx < rowsHere * CH8; idx += 256) {
          int jr = idx / CH8, s = idx - jr * CH8;
          int gr = cb + jr; if (gr > T2 - 1) gr = T2 - 1;
          *(float4*)(colz + jr * STR + s * 16) = *(const float4*)(zbb + (size_t)gr * C + s * 8);
        }
        __syncthreads();
      }
      int ntiles = rowsHere >> 4;
      for (int ct = 0; ct < ntiles; ++ct) {
        int cj0 = cb + ct * 16;
        f32x4 d = {0.f, 0.f, 0.f, 0.f};
#pragma unroll
        for (int ks = 0; ks < KST; ++ks) {
          short8 bv = *(const short8*)(colz + (ct * 16 + l15) * STR + ks * 64 + l4 * 16);
          d = __builtin_amdgcn_mfma_f32_16x16x32_bf16(af[ks], bv, d, 0, 0, 0);
        }
        bool special = (cj0 == i0) || (cj0 + 16 > T2);
        int jg = cj0 + l15;
        if (pass == 0) {
          if (special) {
#pragma unroll
            for (int r = 0; r < 4; ++r) {
              int ig = i0 + l4 * 4 + r;
              if (jg < T2 && jg != ig) M[r] = fmaxf(M[r], d[r]);
            }
          } else {
#pragma unroll
            for (int r = 0; r < 4; ++r) M[r] = fmaxf(M[r], d[r]);
          }
        } else {
          if (special) {
#pragma unroll
            for (int r = 0; r < 4; ++r) {
              int ig = i0 + l4 * 4 + r;
              se[r] += (jg < T2 && jg != ig) ? __expf(d[r] - M[r]) : 0.f;
            }
          } else {
#pragma unroll
            for (int r = 0; r < 4; ++r) se[r] += __expf(d[r] - M[r]);
          }
        }
      }
    }
  }
  float tot = 0.f;
#pragma unroll
  for (int r = 0; r < 4; ++r) {
#pragma unroll
    for (int off = 1; off < 16; off <<= 1) se[r] += __shfl_xor(se[r], off);
    int ig = i0 + l4 * 4 + r;
    if (l15 == 0 && ig < T2) {
      int ii = ig < T ? ig : ig - T;
      tot += roww[ii] * (M[r] + __logf(se[r]));
    }
  }
  block_acc256(tot, scale, acc);
}

// ---------- band wdot for temporal loss ----------
template <int C>
__launch_bounds__(256)
__global__ void band_k(const __hip_bfloat16* __restrict__ zb, const float* __restrict__ ftab,
                       int T, double scale, double* __restrict__ acc) {
  __shared__ float y[78][C + 1];
  __shared__ float f[8];
  const int tid = threadIdx.x;
  const int b = blockIdx.y, ii0 = blockIdx.x * 64;
  const int T2 = 2 * T;
  if (tid < 8) f[tid] = ftab[tid];
  const __hip_bfloat16* zbb = zb + (size_t)b * T2 * C;
  for (int idx = tid; idx < 78 * C; idx += 256) {
    int rr = idx / C, k = idx - rr * C;
    int ii = ii0 - 7 + rr;
    float v = 0.f;
    if (ii >= 0 && ii < T)
      v = __bfloat162float(zbb[(size_t)ii * C + k]) +
          __bfloat162float(zbb[(size_t)(T + ii) * C + k]);
    y[rr][k] = v;
  }
  float p2 = 0.f;
  for (int idx = tid; idx < 64 * C; idx += 256) {
    int rr = idx / C, k = idx - rr * C;
    int ii = ii0 + rr;
    if (ii < T) {
      float v1 = __bfloat162float(zbb[(size_t)ii * C + k]);
      float v2 = __bfloat162float(zbb[(size_t)(T + ii) * C + k]);
      p2 = fmaf(v1, v1, p2); p2 = fmaf(v2, v2, p2);
    }
  }
  __syncthreads();
  const int m = tid & 63, q = tid >> 6;
  float p = 0.f;
  if (ii0 + m < T) {
    int rr = m + 7;
    constexpr int SL = C / 4;
    for (int k = q * SL; k < (q + 1) * SL; ++k) {
      float g = f[0] * y[rr][k];
#pragma unroll
      for (int dd = 1; dd < 8; ++dd) g = fmaf(f[dd], y[rr - dd][k] + y[rr + dd][k], g);
      p = fmaf(y[rr][k], g, p);
    }
  }
  block_acc256(f[0] * p2 - p, scale, acc);
}

// ---------- MFMA instance contrastive ----------
template <int C>
__launch_bounds__(256)
__global__ void inst_mfma_k(const __hip_bfloat16* __restrict__ zb,
                            const float* __restrict__ sl,
                            const float* __restrict__ slrs,
                            int T, double scale, double* __restrict__ acc) {
  constexpr int KST = C / 32;
  constexpr int STR = 2 * C + 16;
  constexpr int CH8 = C / 8;
  __shared__ float4 rz4[128 * STR / 16];
  __shared__ float ssh[64][65];
  char* rz = (char*)rz4;
  const int tid = threadIdx.x;
  const int wave = tid >> 6, lane = tid & 63, l15 = lane & 15, l4 = lane >> 4;
  const int t = blockIdx.x;
  const int T2 = 2 * T;
  for (int idx = tid; idx < 128 * CH8; idx += 256) {
    int r = idx / CH8, s = idx - r * CH8;
    size_t grow = (size_t)(r & 63) * T2 + ((r < 64) ? t : T + t);
    *(float4*)(rz + r * STR + s * 16) = *(const float4*)(zb + grow * C + s * 8);
  }
  for (int u = tid; u < 4096; u += 256) ssh[u >> 6][u & 63] = sl[u];
  __syncthreads();

  short8 af[2][KST];
#pragma unroll
  for (int rt = 0; rt < 2; ++rt) {
    int row = wave * 32 + rt * 16 + l15;
#pragma unroll
    for (int ks = 0; ks < KST; ++ks)
      af[rt][ks] = *(const short8*)(rz + row * STR + ks * 64 + l4 * 16);
  }
  float M[2][4], se[2][4];
#pragma unroll
  for (int rt = 0; rt < 2; ++rt)
#pragma unroll
    for (int r = 0; r < 4; ++r) { M[rt][r] = -3.0e38f; se[rt][r] = 0.f; }
  float wdot = 0.f;

  for (int pass = 0; pass < 2; ++pass) {
    if (pass) {
#pragma unroll
      for (int rt = 0; rt < 2; ++rt)
#pragma unroll
        for (int r = 0; r < 4; ++r)
#pragma unroll
          for (int off = 1; off < 16; off <<= 1)
            M[rt][r] = fmaxf(M[rt][r], __shfl_xor(M[rt][r], off));
    }
#pragma unroll
    for (int rt = 0; rt < 2; ++rt) {
      int ri0 = wave * 32 + rt * 16;
      for (int ct = 0; ct < 8; ++ct) {
        int cj0 = ct * 16;
        f32x4 d = {0.f, 0.f, 0.f, 0.f};
#pragma unroll
        for (int ks = 0; ks < KST; ++ks) {
          short8 bv = *(const short8*)(rz + (cj0 + l15) * STR + ks * 64 + l4 * 16);
          d = __builtin_amdgcn_mfma_f32_16x16x32_bf16(af[rt][ks], bv, d, 0, 0, 0);
        }
        bool diag = (ri0 == cj0);
        int jg = cj0 + l15;
        if (pass == 0) {
#pragma unroll
          for (int r = 0; r < 4; ++r) {
            int ig = ri0 + l4 * 4 + r;
            if (!diag || jg != ig) M[rt][r] = fmaxf(M[rt][r], d[r]);
          }
        } else {
          int bj = jg & 63;
#pragma unroll
          for (int r = 0; r < 4; ++r) {
            int ig = ri0 + l4 * 4 + r;
            bool v = (!diag || jg != ig);
            se[rt][r] += v ? __expf(d[r] - M[rt][r]) : 0.f;
            wdot += v ? ssh[ig & 63][bj] * d[r] : 0.f;
          }
        }
      }
    }
  }
  float tot = -wdot;
#pragma unroll
  for (int rt = 0; rt < 2; ++rt)
#pragma unroll
    for (int r = 0; r < 4; ++r) {
#pragma unroll
      for (int off = 1; off < 16; off <<= 1) se[rt][r] += __shfl_xor(se[rt][r], off);
      if (l15 == 0) {
        int ig = wave * 32 + rt * 16 + l4 * 4 + r;
        int bi = ig & 63;
        float rw = 2.f * slrs[bi] - ssh[bi][bi];
        tot += rw * (M[rt][r] + __logf(se[rt][r]));
      }
    }
  block_acc256(tot, scale, acc);
}

// final FC: lg[n,:] = a[n,:] @ wf + bf ; block per n, 1024 thr
__global__ void fc_k(const float* __restrict__ a, const float* __restrict__ wf,
                     const float* __restrict__ bf, float* __restrict__ lg) {
  int n = blockIdx.x;
  float accv[5] = {0.f, 0.f, 0.f, 0.f, 0.f};
  for (int f = threadIdx.x; f < 16640; f += 1024) {
    float av = a[(size_t)n * 16640 + f];
    const float* wr = wf + (size_t)f * 5;
#pragma unroll
    for (int k = 0; k < 5; ++k) accv[k] = fmaf(av, wr[k], accv[k]);
  }
  __shared__ float red[16][5];
#pragma unroll
  for (int k = 0; k < 5; ++k) {
    float v = accv[k];
#pragma unroll
    for (int off = 32; off; off >>= 1) v += __shfl_down(v, off);
    if ((threadIdx.x & 63) == 0) red[threadIdx.x >> 6][k] = v;
  }
  __syncthreads();
  if (threadIdx.x == 0) {
#pragma unroll
    for (int k = 0; k < 5; ++k) {
      float s = bf[k];
#pragma unroll
      for (int i = 0; i < 16; ++i) s += red[i][k];
      lg[n * 5 + k] = s;
    }
  }
}

__global__ void fin_k(const double* acc, float* out_loss) { *out_loss = (float)(*acc); }

extern "C" void kernel_launch(void* const* d_in, const int* in_sizes, int n_in,
                              void* d_out, int out_size, void* d_ws, size_t ws_size,
                              hipStream_t stream) {
  const float* aug[2] = {(const float*)d_in[0], (const float*)d_in[1]};
  const float* sl = (const float*)d_in[2];
  const float* wconv[3] = {(const float*)d_in[3], (const float*)d_in[6], (const float*)d_in[9]};
  const float* gam[3]   = {(const float*)d_in[4], (const float*)d_in[7], (const float*)d_in[10]};
  const float* bet[3]   = {(const float*)d_in[5], (const float*)d_in[8], (const float*)d_in[11]};
  const float* wf = (const float*)d_in[12];
  const float* bf = (const float*)d_in[13];
  float* out = (float*)d_out;
  float* ws = (float*)d_ws;
  if (ws_size < (size_t)WS_TOTAL * sizeof(float)) return;  // need ~32 MB scratch

  double* acc = (double*)(ws + WS_ACC);
  float* bnA = ws + WS_BNA;
  float* bnB = ws + WS_BNB;
  float* ftab = ws + WS_FTAB;
  float* roww = ws + WS_ROWW;
  float* slrs = ws + WS_SLRS;
  short* wbf[3] = {(short*)(ws + WS_WBF1), (short*)(ws + WS_WBF2), (short*)(ws + WS_WBF3)};
  float* partS = ws + WS_PART1;
  float* partS2 = ws + WS_PART2;
  float* convb = ws + WS_CONV;
  __hip_bfloat16* zb16 = (__hip_bfloat16*)(ws + WS_ZB16);

  const int Cin[3]  = {1, 32, 64};
  const int Cout[3] = {32, 64, 128};
  const int Lin[3]  = {1024, 513, 258};
  const int Lc[3]   = {1025, 514, 259};
  const int Tarr[3] = {513, 258, 130};
  const float sig[3] = {2.f, 4.f, 8.f};
  const int Ktot[3] = {32, 256, 512};

  float* A1 = out + O_A1;
  float* A2 = out + O_A2;

  init_k<<<1, 64, 0, stream>>>(acc, sl, slrs);
  for (int d = 0; d < 3; ++d) {
    int total = Cout[d] * Ktot[d];
    wprep_k<<<(total + 255) / 256, 256, 0, stream>>>(wconv[d], wbf[d], Cin[d] * 8, Ktot[d], total);
  }

  for (int d = 0; d < 3; ++d) {
    int T = Tarr[d];
    int T2 = 2 * T;
    dim3 cg((Lc[d] + 63) / 64, BB);
    int nblk = cg.x * BB;
    for (int s = 0; s < 2; ++s) {
      const float* xin;
      float* pdst;
      if (d == 0)      { xin = aug[s];                               pdst = (s == 0) ? ws + WS_PA1 : ws + WS_PB1; }
      else if (d == 1) { xin = (s == 0) ? ws + WS_PA1 : ws + WS_PB1; pdst = (s == 0) ? ws + WS_PA2 : ws + WS_PB2; }
      else             { xin = (s == 0) ? ws + WS_PA2 : ws + WS_PB2; pdst = (s == 0) ? A1 : A2; }

      switch (d) {
        case 0: conv_mfma_k<1, 32, 4><<<cg, 256, 0, stream>>>(xin, wbf[0], convb, partS, partS2, Lin[d], Lc[d]); break;
        case 1: conv_mfma_k<32, 64, 16><<<cg, 256, 0, stream>>>(xin, wbf[1], convb, partS, partS2, Lin[d], Lc[d]); break;
        default: conv_mfma_k<64, 128, 16><<<cg, 256, 0, stream>>>(xin, wbf[2], convb, partS, partS2, Lin[d], Lc[d]); break;
      }
      stats2_k<<<Cout[d], 256, 0, stream>>>(partS, partS2, gam[d], bet[d], bnA, bnB, nblk, BB * Lc[d]);
      dim3 pg((T + 31) / 32, Cout[d] / 32, BB);
      pool_k<<<pg, dim3(32, 8), 0, stream>>>(convb, bnA, bnB, pdst, zb16, Cout[d], Lc[d], T, s * T);
    }
    ftab_k<<<1, 256, 0, stream>>>(ftab, roww, T, sig[d]);
    double scale = 0.5 / (128.0 * (double)T);
    dim3 tg((T2 + 63) / 64, BB);
    dim3 bg((T + 63) / 64, BB);
    switch (d) {
      case 0:
        temp_mfma_k<32, 512><<<tg, 256, 0, stream>>>(zb16, roww, T, scale, acc);
        band_k<32><<<bg, 256, 0, stream>>>(zb16, ftab, T, scale, acc);
        inst_mfma_k<32><<<T, 256, 0, stream>>>(zb16, sl, slrs, T, scale, acc);
        break;
      case 1:
        temp_mfma_k<64, 256><<<tg, 256, 0, stream>>>(zb16, roww, T, scale, acc);
        band_k<64><<<bg, 256, 0, stream>>>(zb16, ftab, T, scale, acc);
        inst_mfma_k<64><<<T, 256, 0, stream>>>(zb16, sl, slrs, T, scale, acc);
        break;
      default:
        temp_mfma_k<128, 128><<<tg, 256, 0, stream>>>(zb16, roww, T, scale, acc);
        band_k<128><<<bg, 256, 0, stream>>>(zb16, ftab, T, scale, acc);
        inst_mfma_k<128><<<T, 256, 0, stream>>>(zb16, sl, slrs, T, scale, acc);
        break;
    }
  }
  fc_k<<<64, 1024, 0, stream>>>(A1, wf, bf, out + O_LG1);
  fc_k<<<64, 1024, 0, stream>>>(A2, wf, bf, out + O_LG2);
  fin_k<<<1, 1, 0, stream>>>(acc, out + O_LOSS);
}

// Round 7
// 405.828 us; speedup vs baseline: 7.2989x; 1.0665x over previous
//
#include <hip/hip_runtime.h>
#include <hip/hip_bf16.h>
#include <math.h>

#define BB 64
#define PB_STRIDE 1536

typedef __attribute__((ext_vector_type(8))) short short8;
typedef __attribute__((ext_vector_type(4))) float f32x4;

// workspace layout (in floats)
#define WS_ACC   0
#define WS_BNA   4
#define WS_BNB   132
#define WS_FTAB  260
#define WS_ROWW  272
#define WS_SLRS  800
#define WS_WBF1  896      // 512 floats  (1024 bf16)
#define WS_WBF2  1408     // 8192 floats (16384 bf16)
#define WS_WBF3  9600     // 32768 floats (65536 bf16)
#define WS_PART1 42368    // 196608
#define WS_PART2 238976   // 196608
#define WS_CONV  435584
#define SZ_CONV  2121728  // 64*128*259
#define SZ_PBUF  1056768  // 64*64*258
#define WS_PA1   (WS_CONV + SZ_CONV)
#define WS_PA2   (WS_PA1 + SZ_PBUF)
#define WS_PB1   (WS_PA2 + SZ_PBUF)
#define WS_PB2   (WS_PB1 + SZ_PBUF)
#define WS_ZB16  (WS_PB2 + SZ_PBUF)
#define SZ_ZB16  1100000  // floats -> 2.2M bf16 >= 64*260*128
#define WS_TOTAL (WS_ZB16 + SZ_ZB16)

// d_out layout (floats)
#define O_LG1  0
#define O_LG2  320
#define O_A1   640
#define O_A2   (640 + 1064960)
#define O_LOSS (O_A2 + 1064960)

__device__ __forceinline__ short f2bf(float f) {
  unsigned u = __float_as_uint(f);
  u += 0x7FFFu + ((u >> 16) & 1u);
  return (short)(u >> 16);
}

__global__ void init_k(double* acc, const float* __restrict__ sl, float* __restrict__ slrs) {
  if (threadIdx.x == 0) *acc = 0.0;
  int r = threadIdx.x;  // 64 threads
  float s = 0.f;
  for (int c = 0; c < 64; ++c) s += sl[r * 64 + c];
  slrs[r] = s;
}

// fp32 w [O][CIN*8] -> bf16 [O][KTOT] (zero-padded K)
__global__ void wprep_k(const float* __restrict__ w, short* __restrict__ wbf,
                        int nreal, int KTOT, int total) {
  int i = blockIdx.x * 256 + threadIdx.x;
  if (i >= total) return;
  int o = i / KTOT, q = i - o * KTOT;
  short v = 0;
  if (q < nreal) v = f2bf(w[o * nreal + q]);
  wbf[i] = v;
}

// ---------- implicit-GEMM MFMA conv1d (K=8, pad=4) + fused BN partial stats ----------
template <int CIN, int COUT, int CHUNK_CI>
__launch_bounds__(256)
__global__ void conv_mfma_k(const float* __restrict__ x, const short* __restrict__ wbf,
                            float* __restrict__ y, float* __restrict__ part_s,
                            float* __restrict__ part_s2, int Lin, int Lc) {
  constexpr int CIPAD = (CIN < 4) ? 4 : CIN;
  constexpr int KTOT = CIPAD * 8;
  constexpr int NCHUNK = CIPAD / CHUNK_CI;
  constexpr int ROWS8 = CHUNK_CI + 1;
  constexpr int NT = COUT / 16;
  __shared__ short8 a8[64 * ROWS8];
  __shared__ float ps[4][COUT], ps2[4][COUT];
  short* a_lds = (short*)a8;
  const int tid = threadIdx.x;
  const int wave = tid >> 6, lane = tid & 63, l15 = lane & 15, l4 = lane >> 4;
  const int b = blockIdx.y;
  const int j0 = blockIdx.x * 64;
  const float* xb = x + (size_t)b * CIN * Lin;

  f32x4 acc[NT];
#pragma unroll
  for (int nt = 0; nt < NT; ++nt) acc[nt] = (f32x4){0.f, 0.f, 0.f, 0.f};

  for (int ch = 0; ch < NCHUNK; ++ch) {
    __syncthreads();
    for (int idx = tid; idx < 64 * CHUNK_CI; idx += 256) {
      int jr = idx & 63;
      int cc = idx >> 6;
      int ci = ch * CHUNK_CI + cc;
      short8 sv = (short8){0, 0, 0, 0, 0, 0, 0, 0};
      if (ci < CIN) {
        const float* xr = xb + (size_t)ci * Lin;
        int p0 = j0 + jr - 4;
#pragma unroll
        for (int k = 0; k < 8; ++k) {
          int p = p0 + k;
          float v = (p >= 0 && p < Lin) ? xr[p] : 0.f;
          sv[k] = f2bf(v);
        }
      }
      *(short8*)(a_lds + jr * (ROWS8 * 8) + cc * 8) = sv;
    }
    __syncthreads();
#pragma unroll
    for (int ks = 0; ks < CHUNK_CI / 4; ++ks) {
      short8 af = *(const short8*)(a_lds + (wave * 16 + l15) * (ROWS8 * 8) + ks * 32 + l4 * 8);
      const short* wrow = wbf + (size_t)l15 * KTOT + (ch * CHUNK_CI * 8 + ks * 32 + l4 * 8);
#pragma unroll
      for (int nt = 0; nt < NT; ++nt) {
        short8 bv = *(const short8*)(wrow + (size_t)nt * 16 * KTOT);
        acc[nt] = __builtin_amdgcn_mfma_f32_16x16x32_bf16(af, bv, acc[nt], 0, 0, 0);
      }
    }
  }

  const int jbase = j0 + wave * 16 + l4 * 4;
#pragma unroll
  for (int nt = 0; nt < NT; ++nt) {
    int o = nt * 16 + l15;
    float* yr = y + ((size_t)b * COUT + o) * Lc;
    float s = 0.f, s2 = 0.f;
    if (jbase + 3 < Lc) {
      *(float4*)(yr + jbase) = (float4){acc[nt][0], acc[nt][1], acc[nt][2], acc[nt][3]};
#pragma unroll
      for (int r = 0; r < 4; ++r) { float v = acc[nt][r]; s += v; s2 = fmaf(v, v, s2); }
    } else {
#pragma unroll
      for (int r = 0; r < 4; ++r) {
        if (jbase + r < Lc) { float v = acc[nt][r]; yr[jbase + r] = v; s += v; s2 = fmaf(v, v, s2); }
      }
    }
    s  += __shfl_xor(s, 16);  s  += __shfl_xor(s, 32);
    s2 += __shfl_xor(s2, 16); s2 += __shfl_xor(s2, 32);
    if (lane < 16) { ps[wave][nt * 16 + lane] = s; ps2[wave][nt * 16 + lane] = s2; }
  }
  __syncthreads();
  int blk = blockIdx.y * gridDim.x + blockIdx.x;
  for (int o = tid; o < COUT; o += 256) {
    part_s [o * PB_STRIDE + blk] = ps[0][o] + ps[1][o] + ps[2][o] + ps[3][o];
    part_s2[o * PB_STRIDE + blk] = ps2[0][o] + ps2[1][o] + ps2[2][o] + ps2[3][o];
  }
}

// reduce conv partials -> bnA/bnB (deterministic)
__global__ void stats2_k(const float* __restrict__ part_s, const float* __restrict__ part_s2,
                         const float* __restrict__ g, const float* __restrict__ beta,
                         float* __restrict__ bnA, float* __restrict__ bnB, int nblk, int n) {
  int c = blockIdx.x;
  float s = 0.f, s2 = 0.f;
  for (int i = threadIdx.x; i < nblk; i += 256) {
    s += part_s[c * PB_STRIDE + i];
    s2 += part_s2[c * PB_STRIDE + i];
  }
#pragma unroll
  for (int off = 32; off; off >>= 1) { s += __shfl_down(s, off); s2 += __shfl_down(s2, off); }
  __shared__ float as[4], as2[4];
  if ((threadIdx.x & 63) == 0) { as[threadIdx.x >> 6] = s; as2[threadIdx.x >> 6] = s2; }
  __syncthreads();
  if (threadIdx.x == 0) {
    float S = as[0] + as[1] + as[2] + as[3];
    float S2 = as2[0] + as2[1] + as2[2] + as2[3];
    float fn = (float)n;
    float mu = S / fn;
    float var = S2 / fn - mu * mu;
    float A = g[c] * rsqrtf(var + 1e-5f);
    bnA[c] = A;
    bnB[c] = beta[c] - mu * A;
  }
}

// BN-apply + ReLU + maxpool(2,2,pad1)
__global__ void pool_k(const float* __restrict__ conv, const float* __restrict__ bnA,
                       const float* __restrict__ bnB, float* __restrict__ pooled,
                       __hip_bfloat16* __restrict__ zb, int C, int Lc, int Tout, int zoff) {
  __shared__ float tile[32][33];
  int b = blockIdx.z;
  int c0 = blockIdx.y * 32;
  int t0 = blockIdx.x * 32;
  int tx = threadIdx.x;
  int ty = threadIdx.y;
#pragma unroll
  for (int q = 0; q < 4; ++q) {
    int c = c0 + ty + q * 8;
    int t = t0 + tx;
    float v = 0.f;
    if (t < Tout) {
      const float* row = conv + ((size_t)b * C + c) * Lc;
      float A = bnA[c], Bb = bnB[c];
      v = -3.0e38f;
      int p0 = 2 * t - 1;
      if (p0 >= 0) v = fmaxf(v, fmaxf(fmaf(A, row[p0], Bb), 0.f));
      int p1 = 2 * t;
      if (p1 < Lc) v = fmaxf(v, fmaxf(fmaf(A, row[p1], Bb), 0.f));
      pooled[((size_t)b * C + c) * Tout + t] = v;
    }
    tile[ty + q * 8][tx] = v;
  }
  __syncthreads();
  int T2 = 2 * Tout;
#pragma unroll
  for (int q = 0; q < 4; ++q) {
    int t = t0 + ty + q * 8;
    int c = c0 + tx;
    if (t < Tout)
      zb[((size_t)b * T2 + zoff + t) * (size_t)C + c] = __float2bfloat16(tile[tx][ty + q * 8]);
  }
}

// timelag f(d) for d<8 + closed-form row sums
__global__ void ftab_k(float* __restrict__ ftab, float* __restrict__ roww, int T, float sigma) {
  __shared__ float fs[8];
  if (threadIdx.x < 8) {
    double mm = 2.0 / (1.0 + exp((double)threadIdx.x * (double)sigma));
    float f = (mm < 1e-6) ? 0.f : (float)mm;
    ftab[threadIdx.x] = f; fs[threadIdx.x] = f;
  }
  __syncthreads();
  for (int i = threadIdx.x; i < T; i += blockDim.x) {
    float s = fs[0];
#pragma unroll
    for (int d = 1; d < 8; ++d) s += fs[d] * ((i >= d ? 1.f : 0.f) + (i + d < T ? 1.f : 0.f));
    roww[i] = 2.f * s - fs[0];
  }
}

__device__ __forceinline__ void block_acc256(float v, double scale, double* acc) {
#pragma unroll
  for (int off = 32; off; off >>= 1) v += __shfl_down(v, off);
  __shared__ float part[4];
  if ((threadIdx.x & 63) == 0) part[threadIdx.x >> 6] = v;
  __syncthreads();
  if (threadIdx.x == 0)
    atomicAdd(acc, (double)(part[0] + part[1] + part[2] + part[3]) * scale);
}

// ---------- one-pass MFMA temporal contrastive, per-lane online LSE (exact) ----------
// Fragment-packed LDS (conflict-free). Pad columns stage as zero rows -> exp(-M) each,
// subtracted in closed form. wdot handled by band_k.
template <int C, int NC>
__launch_bounds__(256)
__global__ void temp_ol_k(const __hip_bfloat16* __restrict__ zb, const float* __restrict__ roww,
                          int T, double scale, double* __restrict__ acc) {
  constexpr int KST = C / 32;
  constexpr int LOGK = (KST == 1) ? 0 : (KST == 2) ? 1 : 2;
  __shared__ float4 colz4[NC * C / 8];
  char* colz = (char*)colz4;
  const int tid = threadIdx.x;
  const int wave = tid >> 6, lane = tid & 63, l15 = lane & 15, l4 = lane >> 4;
  const int b = blockIdx.y;
  const int T2 = 2 * T;
  const int T2pad = ((T2 + 15) >> 4) << 4;
  const int i0 = blockIdx.x * 64 + wave * 16;
  const __hip_bfloat16* zbb = zb + (size_t)b * T2 * C;

  short8 af[KST];
  {
    int ar = i0 + l15; if (ar > T2 - 1) ar = T2 - 1;
#pragma unroll
    for (int ks = 0; ks < KST; ++ks)
      af[ks] = *(const short8*)(zbb + (size_t)ar * C + ks * 32 + l4 * 8);
  }
  float m[4], se[4];
  int ig[4]; bool dlane[4];
#pragma unroll
  for (int r = 0; r < 4; ++r) {
    ig[r] = i0 + l4 * 4 + r;
    m[r] = 0.f; se[r] = 0.f;
    dlane[r] = (l15 == l4 * 4 + r);
  }

  for (int cb = 0; cb < T2pad; cb += NC) {
    int rows = T2pad - cb; if (rows > NC) rows = NC;
    __syncthreads();
    for (int idx = tid; idx < rows * (C / 8); idx += 256) {
      int ln = idx & 63;
      int ks = (idx >> 6) & (KST - 1);
      int ct = idx >> (6 + LOGK);
      int gr = cb + ct * 16 + (ln & 15);
      short8 sv = (short8){0, 0, 0, 0, 0, 0, 0, 0};
      if (gr < T2) sv = *(const short8*)(zbb + (size_t)gr * C + ks * 32 + (ln >> 4) * 8);
      *(short8*)(colz + (size_t)idx * 16) = sv;
    }
    __syncthreads();
    int ntiles = rows >> 4;
    for (int ct = 0; ct < ntiles; ++ct) {
      int cj0 = cb + ct * 16;
      f32x4 d = {0.f, 0.f, 0.f, 0.f};
#pragma unroll
      for (int ks = 0; ks < KST; ++ks) {
        short8 bv = *(const short8*)(colz + (((ct * KST + ks) << 10) | (lane << 4)));
        d = __builtin_amdgcn_mfma_f32_16x16x32_bf16(af[ks], bv, d, 0, 0, 0);
      }
      bool diagt = (cj0 == i0);
#pragma unroll
      for (int r = 0; r < 4; ++r) {
        float dv = d[r];
        float mn = fmaxf(m[r], dv);
        float senew = se[r] * __expf(m[r] - mn) + __expf(dv - mn);
        if (!(diagt && dlane[r])) { se[r] = senew; m[r] = mn; }
      }
    }
  }

  const float npad = (float)(T2pad - T2);
  float tot = 0.f;
#pragma unroll
  for (int r = 0; r < 4; ++r) {
    float M = m[r];
#pragma unroll
    for (int off = 1; off < 16; off <<= 1) M = fmaxf(M, __shfl_xor(M, off));
    float sv = se[r] * __expf(m[r] - M);
#pragma unroll
    for (int off = 1; off < 16; off <<= 1) sv += __shfl_xor(sv, off);
    sv -= npad * __expf(0.f - M);
    if (l15 == 0 && ig[r] < T2) {
      int ii = ig[r] < T ? ig[r] : ig[r] - T;
      tot += roww[ii] * (M + __logf(fmaxf(sv, 1e-30f)));
    }
  }
  block_acc256(tot, scale, acc);
}

// ---------- band wdot for temporal loss ----------
template <int C>
__launch_bounds__(256)
__global__ void band_k(const __hip_bfloat16* __restrict__ zb, const float* __restrict__ ftab,
                       int T, double scale, double* __restrict__ acc) {
  __shared__ float y[78][C + 1];
  __shared__ float f[8];
  const int tid = threadIdx.x;
  const int b = blockIdx.y, ii0 = blockIdx.x * 64;
  const int T2 = 2 * T;
  if (tid < 8) f[tid] = ftab[tid];
  const __hip_bfloat16* zbb = zb + (size_t)b * T2 * C;
  for (int idx = tid; idx < 78 * C; idx += 256) {
    int rr = idx / C, k = idx - rr * C;
    int ii = ii0 - 7 + rr;
    float v = 0.f;
    if (ii >= 0 && ii < T)
      v = __bfloat162float(zbb[(size_t)ii * C + k]) +
          __bfloat162float(zbb[(size_t)(T + ii) * C + k]);
    y[rr][k] = v;
  }
  float p2 = 0.f;
  for (int idx = tid; idx < 64 * C; idx += 256) {
    int rr = idx / C, k = idx - rr * C;
    int ii = ii0 + rr;
    if (ii < T) {
      float v1 = __bfloat162float(zbb[(size_t)ii * C + k]);
      float v2 = __bfloat162float(zbb[(size_t)(T + ii) * C + k]);
      p2 = fmaf(v1, v1, p2); p2 = fmaf(v2, v2, p2);
    }
  }
  __syncthreads();
  const int m = tid & 63, q = tid >> 6;
  float p = 0.f;
  if (ii0 + m < T) {
    int rr = m + 7;
    constexpr int SL = C / 4;
    for (int k = q * SL; k < (q + 1) * SL; ++k) {
      float g = f[0] * y[rr][k];
#pragma unroll
      for (int dd = 1; dd < 8; ++dd) g = fmaf(f[dd], y[rr - dd][k] + y[rr + dd][k], g);
      p = fmaf(y[rr][k], g, p);
    }
  }
  block_acc256(f[0] * p2 - p, scale, acc);
}

// ---------- one-pass MFMA instance contrastive, per-lane online LSE (exact) ----------
template <int C>
__launch_bounds__(256)
__global__ void inst_ol_k(const __hip_bfloat16* __restrict__ zb, const float* __restrict__ sl,
                          const float* __restrict__ slrs,
                          int T, double scale, double* __restrict__ acc) {
  constexpr int KST = C / 32;
  constexpr int LOGK = (KST == 1) ? 0 : (KST == 2) ? 1 : 2;
  __shared__ float4 rz4[128 * C / 8];
  __shared__ float ssh[64][65];
  char* rz = (char*)rz4;
  const int tid = threadIdx.x;
  const int wave = tid >> 6, lane = tid & 63, l15 = lane & 15, l4 = lane >> 4;
  const int t = blockIdx.x;
  const int T2 = 2 * T;
  for (int idx = tid; idx < 128 * (C / 8); idx += 256) {
    int ln = idx & 63;
    int ks = (idx >> 6) & (KST - 1);
    int t16 = idx >> (6 + LOGK);
    int r = t16 * 16 + (ln & 15);
    size_t grow = (size_t)(r & 63) * T2 + ((r < 64) ? t : T + t);
    *(short8*)(rz + (size_t)idx * 16) = *(const short8*)(zb + grow * C + ks * 32 + (ln >> 4) * 8);
  }
  for (int u = tid; u < 4096; u += 256) ssh[u >> 6][u & 63] = sl[u];
  __syncthreads();

  short8 af[2][KST];
#pragma unroll
  for (int rt = 0; rt < 2; ++rt)
#pragma unroll
    for (int ks = 0; ks < KST; ++ks)
      af[rt][ks] = *(const short8*)(rz + ((((wave * 2 + rt) * KST + ks) << 10) | (lane << 4)));
  float m[2][4], se[2][4];
  int bi2[2][4]; bool dlane[4];
#pragma unroll
  for (int r = 0; r < 4; ++r) dlane[r] = (l15 == l4 * 4 + r);
#pragma unroll
  for (int rt = 0; rt < 2; ++rt)
#pragma unroll
    for (int r = 0; r < 4; ++r) {
      int igv = wave * 32 + rt * 16 + l4 * 4 + r;
      m[rt][r] = 0.f; se[rt][r] = 0.f;
      bi2[rt][r] = igv & 63;
    }
  float wdot = 0.f;

#pragma unroll
  for (int rt = 0; rt < 2; ++rt) {
    int ri0 = wave * 32 + rt * 16;
    for (int ct = 0; ct < 8; ++ct) {
      f32x4 d = {0.f, 0.f, 0.f, 0.f};
#pragma unroll
      for (int ks = 0; ks < KST; ++ks) {
        short8 bv = *(const short8*)(rz + (((ct * KST + ks) << 10) | (lane << 4)));
        d = __builtin_amdgcn_mfma_f32_16x16x32_bf16(af[rt][ks], bv, d, 0, 0, 0);
      }
      bool diagt = (ri0 == ct * 16);
      int bj = (ct * 16 + l15) & 63;
#pragma unroll
      for (int r = 0; r < 4; ++r) {
        float dv = d[r];
        float mn = fmaxf(m[rt][r], dv);
        float senew = se[rt][r] * __expf(m[rt][r] - mn) + __expf(dv - mn);
        if (!(diagt && dlane[r])) {
          se[rt][r] = senew; m[rt][r] = mn;
          wdot = fmaf(ssh[bi2[rt][r]][bj], dv, wdot);
        }
      }
    }
  }
  float tot = -wdot;
#pragma unroll
  for (int rt = 0; rt < 2; ++rt)
#pragma unroll
    for (int r = 0; r < 4; ++r) {
      float M = m[rt][r];
#pragma unroll
      for (int off = 1; off < 16; off <<= 1) M = fmaxf(M, __shfl_xor(M, off));
      float sv = se[rt][r] * __expf(m[rt][r] - M);
#pragma unroll
      for (int off = 1; off < 16; off <<= 1) sv += __shfl_xor(sv, off);
      if (l15 == 0) {
        int bi = bi2[rt][r];
        float rw = 2.f * slrs[bi] - ssh[bi][bi];
        tot += rw * (M + __logf(fmaxf(sv, 1e-30f)));
      }
    }
  block_acc256(tot, scale, acc);
}

// final FC: lg[n,:] = a[n,:] @ wf + bf ; block per n, 1024 thr
__global__ void fc_k(const float* __restrict__ a, const float* __restrict__ wf,
                     const float* __restrict__ bf, float* __restrict__ lg) {
  int n = blockIdx.x;
  float accv[5] = {0.f, 0.f, 0.f, 0.f, 0.f};
  for (int f = threadIdx.x; f < 16640; f += 1024) {
    float av = a[(size_t)n * 16640 + f];
    const float* wr = wf + (size_t)f * 5;
#pragma unroll
    for (int k = 0; k < 5; ++k) accv[k] = fmaf(av, wr[k], accv[k]);
  }
  __shared__ float red[16][5];
#pragma unroll
  for (int k = 0; k < 5; ++k) {
    float v = accv[k];
#pragma unroll
    for (int off = 32; off; off >>= 1) v += __shfl_down(v, off);
    if ((threadIdx.x & 63) == 0) red[threadIdx.x >> 6][k] = v;
  }
  __syncthreads();
  if (threadIdx.x == 0) {
#pragma unroll
    for (int k = 0; k < 5; ++k) {
      float s = bf[k];
#pragma unroll
      for (int i = 0; i < 16; ++i) s += red[i][k];
      lg[n * 5 + k] = s;
    }
  }
}

__global__ void fin_k(const double* acc, float* out_loss) { *out_loss = (float)(*acc); }

extern "C" void kernel_launch(void* const* d_in, const int* in_sizes, int n_in,
                              void* d_out, int out_size, void* d_ws, size_t ws_size,
                              hipStream_t stream) {
  const float* aug[2] = {(const float*)d_in[0], (const float*)d_in[1]};
  const float* sl = (const float*)d_in[2];
  const float* wconv[3] = {(const float*)d_in[3], (const float*)d_in[6], (const float*)d_in[9]};
  const float* gam[3]   = {(const float*)d_in[4], (const float*)d_in[7], (const float*)d_in[10]};
  const float* bet[3]   = {(const float*)d_in[5], (const float*)d_in[8], (const float*)d_in[11]};
  const float* wf = (const float*)d_in[12];
  const float* bf = (const float*)d_in[13];
  float* out = (float*)d_out;
  float* ws = (float*)d_ws;
  if (ws_size < (size_t)WS_TOTAL * sizeof(float)) return;

  double* acc = (double*)(ws + WS_ACC);
  float* bnA = ws + WS_BNA;
  float* bnB = ws + WS_BNB;
  float* ftab = ws + WS_FTAB;
  float* roww = ws + WS_ROWW;
  float* slrs = ws + WS_SLRS;
  short* wbf[3] = {(short*)(ws + WS_WBF1), (short*)(ws + WS_WBF2), (short*)(ws + WS_WBF3)};
  float* partS = ws + WS_PART1;
  float* partS2 = ws + WS_PART2;
  float* convb = ws + WS_CONV;
  __hip_bfloat16* zb16 = (__hip_bfloat16*)(ws + WS_ZB16);

  const int Cin[3]  = {1, 32, 64};
  const int Cout[3] = {32, 64, 128};
  const int Lin[3]  = {1024, 513, 258};
  const int Lc[3]   = {1025, 514, 259};
  const int Tarr[3] = {513, 258, 130};
  const float sig[3] = {2.f, 4.f, 8.f};
  const int Ktot[3] = {32, 256, 512};

  float* A1 = out + O_A1;
  float* A2 = out + O_A2;

  init_k<<<1, 64, 0, stream>>>(acc, sl, slrs);
  for (int d = 0; d < 3; ++d) {
    int total = Cout[d] * Ktot[d];
    wprep_k<<<(total + 255) / 256, 256, 0, stream>>>(wconv[d], wbf[d], Cin[d] * 8, Ktot[d], total);
  }

  for (int d = 0; d < 3; ++d) {
    int T = Tarr[d];
    int T2 = 2 * T;
    dim3 cg((Lc[d] + 63) / 64, BB);
    int nblk = cg.x * BB;
    for (int s = 0; s < 2; ++s) {
      const float* xin;
      float* pdst;
      if (d == 0)      { xin = aug[s];                               pdst = (s == 0) ? ws + WS_PA1 : ws + WS_PB1; }
      else if (d == 1) { xin = (s == 0) ? ws + WS_PA1 : ws + WS_PB1; pdst = (s == 0) ? ws + WS_PA2 : ws + WS_PB2; }
      else             { xin = (s == 0) ? ws + WS_PA2 : ws + WS_PB2; pdst = (s == 0) ? A1 : A2; }

      switch (d) {
        case 0: conv_mfma_k<1, 32, 4><<<cg, 256, 0, stream>>>(xin, wbf[0], convb, partS, partS2, Lin[d], Lc[d]); break;
        case 1: conv_mfma_k<32, 64, 16><<<cg, 256, 0, stream>>>(xin, wbf[1], convb, partS, partS2, Lin[d], Lc[d]); break;
        default: conv_mfma_k<64, 128, 16><<<cg, 256, 0, stream>>>(xin, wbf[2], convb, partS, partS2, Lin[d], Lc[d]); break;
      }
      stats2_k<<<Cout[d], 256, 0, stream>>>(partS, partS2, gam[d], bet[d], bnA, bnB, nblk, BB * Lc[d]);
      dim3 pg((T + 31) / 32, Cout[d] / 32, BB);
      pool_k<<<pg, dim3(32, 8), 0, stream>>>(convb, bnA, bnB, pdst, zb16, Cout[d], Lc[d], T, s * T);
    }
    ftab_k<<<1, 256, 0, stream>>>(ftab, roww, T, sig[d]);
    double scale = 0.5 / (128.0 * (double)T);
    dim3 tg((T2 + 63) / 64, BB);
    dim3 bg((T + 63) / 64, BB);
    switch (d) {
      case 0:
        temp_ol_k<32, 512><<<tg, 256, 0, stream>>>(zb16, roww, T, scale, acc);
        band_k<32><<<bg, 256, 0, stream>>>(zb16, ftab, T, scale, acc);
        inst_ol_k<32><<<T, 256, 0, stream>>>(zb16, sl, slrs, T, scale, acc);
        break;
      case 1:
        temp_ol_k<64, 256><<<tg, 256, 0, stream>>>(zb16, roww, T, scale, acc);
        band_k<64><<<bg, 256, 0, stream>>>(zb16, ftab, T, scale, acc);
        inst_ol_k<64><<<T, 256, 0, stream>>>(zb16, sl, slrs, T, scale, acc);
        break;
      default:
        temp_ol_k<128, 128><<<tg, 256, 0, stream>>>(zb16, roww, T, scale, acc);
        band_k<128><<<bg, 256, 0, stream>>>(zb16, ftab, T, scale, acc);
        inst_ol_k<128><<<T, 256, 0, stream>>>(zb16, sl, slrs, T, scale, acc);
        break;
    }
  }
  fc_k<<<64, 1024, 0, stream>>>(A1, wf, bf, out + O_LG1);
  fc_k<<<64, 1024, 0, stream>>>(A2, wf, bf, out + O_LG2);
  fin_k<<<1, 1, 0, stream>>>(acc, out + O_LOSS);
}

// Round 8
// 403.422 us; speedup vs baseline: 7.3424x; 1.0060x over previous
//
#include <hip/hip_runtime.h>
#include <hip/hip_bf16.h>
#include <math.h>

#define BB 64
#define PB_STRIDE 1536

typedef __attribute__((ext_vector_type(8))) short short8;
typedef __attribute__((ext_vector_type(4))) float f32x4;

// workspace layout (in floats)
#define WS_ACC   0
#define WS_BNA   4
#define WS_BNB   132
#define WS_FTAB  260
#define WS_ROWW  272
#define WS_SLRS  800
#define WS_WBF1  896      // 512 floats  (1024 bf16)
#define WS_WBF2  1408     // 8192 floats (16384 bf16)
#define WS_WBF3  9600     // 32768 floats (65536 bf16)
#define WS_PART1 42368    // 196608 (aliased: norms[b][T2] after stats2 consumed)
#define WS_PART2 238976   // 196608 (aliased: bmax[64])
#define WS_CONV  435584
#define SZ_CONV  2121728  // 64*128*259
#define SZ_PBUF  1056768  // 64*64*258
#define WS_PA1   (WS_CONV + SZ_CONV)
#define WS_PA2   (WS_PA1 + SZ_PBUF)
#define WS_PB1   (WS_PA2 + SZ_PBUF)
#define WS_PB2   (WS_PB1 + SZ_PBUF)
#define WS_ZB16  (WS_PB2 + SZ_PBUF)
#define SZ_ZB16  1100000  // floats -> 2.2M bf16 >= 64*260*128
#define WS_TOTAL (WS_ZB16 + SZ_ZB16)

// d_out layout (floats)
#define O_LG1  0
#define O_LG2  320
#define O_A1   640
#define O_A2   (640 + 1064960)
#define O_LOSS (O_A2 + 1064960)

#define LOG2E 1.44269504f
#define LN2   0.69314718f

__device__ __forceinline__ short f2bf(float f) {
  unsigned u = __float_as_uint(f);
  u += 0x7FFFu + ((u >> 16) & 1u);
  return (short)(u >> 16);
}
__device__ __forceinline__ float bfb2f(short s) {
  return __uint_as_float(((unsigned)(unsigned short)s) << 16);
}

__global__ void init_k(double* acc, const float* __restrict__ sl, float* __restrict__ slrs) {
  if (threadIdx.x == 0) *acc = 0.0;
  int r = threadIdx.x;  // 64 threads
  float s = 0.f;
  for (int c = 0; c < 64; ++c) s += sl[r * 64 + c];
  slrs[r] = s;
}

// fp32 w [O][CIN*8] -> bf16 [O][KTOT] (zero-padded K)
__global__ void wprep_k(const float* __restrict__ w, short* __restrict__ wbf,
                        int nreal, int KTOT, int total) {
  int i = blockIdx.x * 256 + threadIdx.x;
  if (i >= total) return;
  int o = i / KTOT, q = i - o * KTOT;
  short v = 0;
  if (q < nreal) v = f2bf(w[o * nreal + q]);
  wbf[i] = v;
}

// ---------- implicit-GEMM MFMA conv1d (K=8, pad=4) + fused BN partial stats ----------
template <int CIN, int COUT, int CHUNK_CI>
__launch_bounds__(256)
__global__ void conv_mfma_k(const float* __restrict__ x, const short* __restrict__ wbf,
                            float* __restrict__ y, float* __restrict__ part_s,
                            float* __restrict__ part_s2, int Lin, int Lc) {
  constexpr int CIPAD = (CIN < 4) ? 4 : CIN;
  constexpr int KTOT = CIPAD * 8;
  constexpr int NCHUNK = CIPAD / CHUNK_CI;
  constexpr int ROWS8 = CHUNK_CI + 1;
  constexpr int NT = COUT / 16;
  __shared__ short8 a8[64 * ROWS8];
  __shared__ float ps[4][COUT], ps2[4][COUT];
  short* a_lds = (short*)a8;
  const int tid = threadIdx.x;
  const int wave = tid >> 6, lane = tid & 63, l15 = lane & 15, l4 = lane >> 4;
  const int b = blockIdx.y;
  const int j0 = blockIdx.x * 64;
  const float* xb = x + (size_t)b * CIN * Lin;

  f32x4 acc[NT];
#pragma unroll
  for (int nt = 0; nt < NT; ++nt) acc[nt] = (f32x4){0.f, 0.f, 0.f, 0.f};

  for (int ch = 0; ch < NCHUNK; ++ch) {
    __syncthreads();
    for (int idx = tid; idx < 64 * CHUNK_CI; idx += 256) {
      int jr = idx & 63;
      int cc = idx >> 6;
      int ci = ch * CHUNK_CI + cc;
      short8 sv = (short8){0, 0, 0, 0, 0, 0, 0, 0};
      if (ci < CIN) {
        const float* xr = xb + (size_t)ci * Lin;
        int p0 = j0 + jr - 4;
#pragma unroll
        for (int k = 0; k < 8; ++k) {
          int p = p0 + k;
          float v = (p >= 0 && p < Lin) ? xr[p] : 0.f;
          sv[k] = f2bf(v);
        }
      }
      *(short8*)(a_lds + jr * (ROWS8 * 8) + cc * 8) = sv;
    }
    __syncthreads();
#pragma unroll
    for (int ks = 0; ks < CHUNK_CI / 4; ++ks) {
      short8 af = *(const short8*)(a_lds + (wave * 16 + l15) * (ROWS8 * 8) + ks * 32 + l4 * 8);
      const short* wrow = wbf + (size_t)l15 * KTOT + (ch * CHUNK_CI * 8 + ks * 32 + l4 * 8);
#pragma unroll
      for (int nt = 0; nt < NT; ++nt) {
        short8 bv = *(const short8*)(wrow + (size_t)nt * 16 * KTOT);
        acc[nt] = __builtin_amdgcn_mfma_f32_16x16x32_bf16(af, bv, acc[nt], 0, 0, 0);
      }
    }
  }

  const int jbase = j0 + wave * 16 + l4 * 4;
#pragma unroll
  for (int nt = 0; nt < NT; ++nt) {
    int o = nt * 16 + l15;
    float* yr = y + ((size_t)b * COUT + o) * Lc;
    float s = 0.f, s2 = 0.f;
    if (jbase + 3 < Lc) {
      *(float4*)(yr + jbase) = (float4){acc[nt][0], acc[nt][1], acc[nt][2], acc[nt][3]};
#pragma unroll
      for (int r = 0; r < 4; ++r) { float v = acc[nt][r]; s += v; s2 = fmaf(v, v, s2); }
    } else {
#pragma unroll
      for (int r = 0; r < 4; ++r) {
        if (jbase + r < Lc) { float v = acc[nt][r]; yr[jbase + r] = v; s += v; s2 = fmaf(v, v, s2); }
      }
    }
    s  += __shfl_xor(s, 16);  s  += __shfl_xor(s, 32);
    s2 += __shfl_xor(s2, 16); s2 += __shfl_xor(s2, 32);
    if (lane < 16) { ps[wave][nt * 16 + lane] = s; ps2[wave][nt * 16 + lane] = s2; }
  }
  __syncthreads();
  int blk = blockIdx.y * gridDim.x + blockIdx.x;
  for (int o = tid; o < COUT; o += 256) {
    part_s [o * PB_STRIDE + blk] = ps[0][o] + ps[1][o] + ps[2][o] + ps[3][o];
    part_s2[o * PB_STRIDE + blk] = ps2[0][o] + ps2[1][o] + ps2[2][o] + ps2[3][o];
  }
}

// reduce conv partials -> bnA/bnB (deterministic)
__global__ void stats2_k(const float* __restrict__ part_s, const float* __restrict__ part_s2,
                         const float* __restrict__ g, const float* __restrict__ beta,
                         float* __restrict__ bnA, float* __restrict__ bnB, int nblk, int n) {
  int c = blockIdx.x;
  float s = 0.f, s2 = 0.f;
  for (int i = threadIdx.x; i < nblk; i += 256) {
    s += part_s[c * PB_STRIDE + i];
    s2 += part_s2[c * PB_STRIDE + i];
  }
#pragma unroll
  for (int off = 32; off; off >>= 1) { s += __shfl_down(s, off); s2 += __shfl_down(s2, off); }
  __shared__ float as[4], as2[4];
  if ((threadIdx.x & 63) == 0) { as[threadIdx.x >> 6] = s; as2[threadIdx.x >> 6] = s2; }
  __syncthreads();
  if (threadIdx.x == 0) {
    float S = as[0] + as[1] + as[2] + as[3];
    float S2 = as2[0] + as2[1] + as2[2] + as2[3];
    float fn = (float)n;
    float mu = S / fn;
    float var = S2 / fn - mu * mu;
    float A = g[c] * rsqrtf(var + 1e-5f);
    bnA[c] = A;
    bnB[c] = beta[c] - mu * A;
  }
}

// BN-apply + ReLU + maxpool(2,2,pad1)
__global__ void pool_k(const float* __restrict__ conv, const float* __restrict__ bnA,
                       const float* __restrict__ bnB, float* __restrict__ pooled,
                       __hip_bfloat16* __restrict__ zb, int C, int Lc, int Tout, int zoff) {
  __shared__ float tile[32][33];
  int b = blockIdx.z;
  int c0 = blockIdx.y * 32;
  int t0 = blockIdx.x * 32;
  int tx = threadIdx.x;
  int ty = threadIdx.y;
#pragma unroll
  for (int q = 0; q < 4; ++q) {
    int c = c0 + ty + q * 8;
    int t = t0 + tx;
    float v = 0.f;
    if (t < Tout) {
      const float* row = conv + ((size_t)b * C + c) * Lc;
      float A = bnA[c], Bb = bnB[c];
      v = -3.0e38f;
      int p0 = 2 * t - 1;
      if (p0 >= 0) v = fmaxf(v, fmaxf(fmaf(A, row[p0], Bb), 0.f));
      int p1 = 2 * t;
      if (p1 < Lc) v = fmaxf(v, fmaxf(fmaf(A, row[p1], Bb), 0.f));
      pooled[((size_t)b * C + c) * Tout + t] = v;
    }
    tile[ty + q * 8][tx] = v;
  }
  __syncthreads();
  int T2 = 2 * Tout;
#pragma unroll
  for (int q = 0; q < 4; ++q) {
    int t = t0 + ty + q * 8;
    int c = c0 + tx;
    if (t < Tout)
      zb[((size_t)b * T2 + zoff + t) * (size_t)C + c] = __float2bfloat16(tile[tx][ty + q * 8]);
  }
}

// per-row norms of z + per-batch max norm; grid(B), 1024 thr; deterministic
template <int C>
__global__ void norms_k(const __hip_bfloat16* __restrict__ zb, float* __restrict__ norms,
                        float* __restrict__ bmax, int T2) {
  int b = blockIdx.x;
  const __hip_bfloat16* zbb = zb + (size_t)b * T2 * C;
  int q = threadIdx.x & 3, r0 = threadIdx.x >> 2;
  float nm = 0.f;
  for (int r = r0; r < T2; r += 256) {
    float s = 0.f;
    const __hip_bfloat16* p = zbb + (size_t)r * C + q * (C / 4);
#pragma unroll
    for (int v = 0; v < C / 32; ++v) {
      short8 sv = *(const short8*)(p + v * 8);
#pragma unroll
      for (int e = 0; e < 8; ++e) { float f = bfb2f(sv[e]); s = fmaf(f, f, s); }
    }
    s += __shfl_xor(s, 1); s += __shfl_xor(s, 2);
    float nr = sqrtf(s);
    if (q == 0) norms[(size_t)b * T2 + r] = nr;
    nm = fmaxf(nm, nr);
  }
#pragma unroll
  for (int off = 32; off; off >>= 1) nm = fmaxf(nm, __shfl_xor(nm, off));
  __shared__ float pm[16];
  if ((threadIdx.x & 63) == 0) pm[threadIdx.x >> 6] = nm;
  __syncthreads();
  if (threadIdx.x == 0) {
    float m = 0.f;
#pragma unroll
    for (int i = 0; i < 16; ++i) m = fmaxf(m, pm[i]);
    bmax[b] = m;
  }
}

// timelag f(d) for d<8 + closed-form row sums
__global__ void ftab_k(float* __restrict__ ftab, float* __restrict__ roww, int T, float sigma) {
  __shared__ float fs[8];
  if (threadIdx.x < 8) {
    double mm = 2.0 / (1.0 + exp((double)threadIdx.x * (double)sigma));
    float f = (mm < 1e-6) ? 0.f : (float)mm;
    ftab[threadIdx.x] = f; fs[threadIdx.x] = f;
  }
  __syncthreads();
  for (int i = threadIdx.x; i < T; i += blockDim.x) {
    float s = fs[0];
#pragma unroll
    for (int d = 1; d < 8; ++d) s += fs[d] * ((i >= d ? 1.f : 0.f) + (i + d < T ? 1.f : 0.f));
    roww[i] = 2.f * s - fs[0];
  }
}

__device__ __forceinline__ void block_acc256(float v, double scale, double* acc) {
#pragma unroll
  for (int off = 32; off; off >>= 1) v += __shfl_down(v, off);
  __shared__ float part[4];
  if ((threadIdx.x & 63) == 0) part[threadIdx.x >> 6] = v;
  __syncthreads();
  if (threadIdx.x == 0)
    atomicAdd(acc, (double)(part[0] + part[1] + part[2] + part[3]) * scale);
}

// ---------- biased-exp2 one-pass MFMA temporal contrastive ----------
// z >= 0 (post-ReLU/pool) => s in [0, Mh_i], Mh_i = norm_i * max_norm.
// se = sum exp2(s*log2e - B_i), B_i = max(Mh_i*log2e - 110, 0):
//   max term <= 2^110 (sum < 2^121), min term >= 2^min(0,110-Mh*L2E) -- all normal fp32.
template <int C, int NC>
__launch_bounds__(256)
__global__ void temp_b_k(const __hip_bfloat16* __restrict__ zb, const float* __restrict__ roww,
                         const float* __restrict__ norms, const float* __restrict__ bmax,
                         int T, double scale, double* __restrict__ acc) {
  constexpr int KST = C / 32;
  constexpr int LOGK = (KST == 1) ? 0 : (KST == 2) ? 1 : 2;
  __shared__ float4 colz4[NC * C / 8];
  char* colz = (char*)colz4;
  const int tid = threadIdx.x;
  const int wave = tid >> 6, lane = tid & 63, l15 = lane & 15, l4 = lane >> 4;
  const int b = blockIdx.y;
  const int T2 = 2 * T;
  const int T2pad = ((T2 + 15) >> 4) << 4;
  const int i0 = blockIdx.x * 64 + wave * 16;
  const __hip_bfloat16* zbb = zb + (size_t)b * T2 * C;

  short8 af[KST];
  {
    int ar = i0 + l15; if (ar > T2 - 1) ar = T2 - 1;
#pragma unroll
    for (int ks = 0; ks < KST; ++ks)
      af[ks] = *(const short8*)(zbb + (size_t)ar * C + ks * 32 + l4 * 8);
  }
  const float Nb = bmax[b];
  float B[4], se[4];
  int ig[4]; bool dlane[4];
#pragma unroll
  for (int r = 0; r < 4; ++r) {
    ig[r] = i0 + l4 * 4 + r;
    int ix = ig[r] < T2 ? ig[r] : T2 - 1;
    B[r] = fmaxf(norms[(size_t)b * T2 + ix] * Nb * LOG2E - 110.f, 0.f);
    se[r] = 0.f;
    dlane[r] = (l15 == l4 * 4 + r);
  }

  for (int cb = 0; cb < T2pad; cb += NC) {
    int rows = T2pad - cb; if (rows > NC) rows = NC;
    __syncthreads();
    for (int idx = tid; idx < rows * (C / 8); idx += 256) {
      int ln = idx & 63;
      int ks = (idx >> 6) & (KST - 1);
      int ct = idx >> (6 + LOGK);
      int gr = cb + ct * 16 + (ln & 15);
      short8 sv = (short8){0, 0, 0, 0, 0, 0, 0, 0};
      if (gr < T2) sv = *(const short8*)(zbb + (size_t)gr * C + ks * 32 + (ln >> 4) * 8);
      *(short8*)(colz + (size_t)idx * 16) = sv;
    }
    __syncthreads();
    int ntiles = rows >> 4;
    for (int ct = 0; ct < ntiles; ++ct) {
      int cj0 = cb + ct * 16;
      f32x4 d = {0.f, 0.f, 0.f, 0.f};
#pragma unroll
      for (int ks = 0; ks < KST; ++ks) {
        short8 bv = *(const short8*)(colz + (((ct * KST + ks) << 10) | (lane << 4)));
        d = __builtin_amdgcn_mfma_f32_16x16x32_bf16(af[ks], bv, d, 0, 0, 0);
      }
      if (cj0 == i0) {  // wave-uniform diag tile
#pragma unroll
        for (int r = 0; r < 4; ++r)
          se[r] += dlane[r] ? 0.f : exp2f(fmaf(d[r], LOG2E, -B[r]));
      } else {
#pragma unroll
        for (int r = 0; r < 4; ++r)
          se[r] += exp2f(fmaf(d[r], LOG2E, -B[r]));
      }
    }
  }

  const float npad = (float)(T2pad - T2);
  float tot = 0.f;
#pragma unroll
  for (int r = 0; r < 4; ++r) {
    float sv = se[r];
#pragma unroll
    for (int off = 1; off < 16; off <<= 1) sv += __shfl_xor(sv, off);
    sv -= npad * exp2f(-B[r]);   // pad columns: s=0 -> exactly 2^-B each
    if (l15 == 0 && ig[r] < T2) {
      int ii = ig[r] < T ? ig[r] : ig[r] - T;
      float lse = (__log2f(fmaxf(sv, 1e-37f)) + B[r]) * LN2;
      tot += roww[ii] * lse;
    }
  }
  block_acc256(tot, scale, acc);
}

// ---------- band wdot for temporal loss ----------
template <int C>
__launch_bounds__(256)
__global__ void band_k(const __hip_bfloat16* __restrict__ zb, const float* __restrict__ ftab,
                       int T, double scale, double* __restrict__ acc) {
  __shared__ float y[78][C + 1];
  __shared__ float f[8];
  const int tid = threadIdx.x;
  const int b = blockIdx.y, ii0 = blockIdx.x * 64;
  const int T2 = 2 * T;
  if (tid < 8) f[tid] = ftab[tid];
  const __hip_bfloat16* zbb = zb + (size_t)b * T2 * C;
  for (int idx = tid; idx < 78 * C; idx += 256) {
    int rr = idx / C, k = idx - rr * C;
    int ii = ii0 - 7 + rr;
    float v = 0.f;
    if (ii >= 0 && ii < T)
      v = __bfloat162float(zbb[(size_t)ii * C + k]) +
          __bfloat162float(zbb[(size_t)(T + ii) * C + k]);
    y[rr][k] = v;
  }
  float p2 = 0.f;
  for (int idx = tid; idx < 64 * C; idx += 256) {
    int rr = idx / C, k = idx - rr * C;
    int ii = ii0 + rr;
    if (ii < T) {
      float v1 = __bfloat162float(zbb[(size_t)ii * C + k]);
      float v2 = __bfloat162float(zbb[(size_t)(T + ii) * C + k]);
      p2 = fmaf(v1, v1, p2); p2 = fmaf(v2, v2, p2);
    }
  }
  __syncthreads();
  const int m = tid & 63, q = tid >> 6;
  float p = 0.f;
  if (ii0 + m < T) {
    int rr = m + 7;
    constexpr int SL = C / 4;
    for (int k = q * SL; k < (q + 1) * SL; ++k) {
      float g = f[0] * y[rr][k];
#pragma unroll
      for (int dd = 1; dd < 8; ++dd) g = fmaf(f[dd], y[rr - dd][k] + y[rr + dd][k], g);
      p = fmaf(y[rr][k], g, p);
    }
  }
  block_acc256(f[0] * p2 - p, scale, acc);
}

// ---------- biased-exp2 one-pass MFMA instance contrastive ----------
template <int C>
__launch_bounds__(256)
__global__ void inst_b_k(const __hip_bfloat16* __restrict__ zb, const float* __restrict__ sl,
                         const float* __restrict__ slrs, const float* __restrict__ norms,
                         int T, double scale, double* __restrict__ acc) {
  constexpr int KST = C / 32;
  constexpr int LOGK = (KST == 1) ? 0 : (KST == 2) ? 1 : 2;
  __shared__ float4 rz4[128 * C / 8];
  __shared__ float ssh[64][65];
  __shared__ float normsh[128];
  __shared__ float pmx[4];
  char* rz = (char*)rz4;
  const int tid = threadIdx.x;
  const int wave = tid >> 6, lane = tid & 63, l15 = lane & 15, l4 = lane >> 4;
  const int t = blockIdx.x;
  const int T2 = 2 * T;
  for (int idx = tid; idx < 128 * (C / 8); idx += 256) {
    int ln = idx & 63;
    int ks = (idx >> 6) & (KST - 1);
    int t16 = idx >> (6 + LOGK);
    int r = t16 * 16 + (ln & 15);
    size_t grow = (size_t)(r & 63) * T2 + ((r < 64) ? t : T + t);
    *(short8*)(rz + (size_t)idx * 16) = *(const short8*)(zb + grow * C + ks * 32 + (ln >> 4) * 8);
  }
  for (int u = tid; u < 4096; u += 256) ssh[u >> 6][u & 63] = sl[u];
  if (tid < 128) normsh[tid] = norms[(size_t)(tid & 63) * T2 + ((tid < 64) ? t : T + t)];
  __syncthreads();
  float nv = (tid < 128) ? normsh[tid] : 0.f;
#pragma unroll
  for (int off = 32; off; off >>= 1) nv = fmaxf(nv, __shfl_xor(nv, off));
  if (lane == 0) pmx[wave] = nv;
  __syncthreads();
  const float Nt = fmaxf(fmaxf(pmx[0], pmx[1]), fmaxf(pmx[2], pmx[3]));

  short8 af[2][KST];
#pragma unroll
  for (int rt = 0; rt < 2; ++rt)
#pragma unroll
    for (int ks = 0; ks < KST; ++ks)
      af[rt][ks] = *(const short8*)(rz + ((((wave * 2 + rt) * KST + ks) << 10) | (lane << 4)));
  float B[2][4], se[2][4], w4[2][4][4];
  int bi2[2][4]; bool dlane[4];
#pragma unroll
  for (int r = 0; r < 4; ++r) dlane[r] = (l15 == l4 * 4 + r);
#pragma unroll
  for (int rt = 0; rt < 2; ++rt)
#pragma unroll
    for (int r = 0; r < 4; ++r) {
      int igv = wave * 32 + rt * 16 + l4 * 4 + r;
      int bi = igv & 63;
      B[rt][r] = fmaxf(normsh[igv] * Nt * LOG2E - 110.f, 0.f);
      se[rt][r] = 0.f;
      bi2[rt][r] = bi;
#pragma unroll
      for (int c4 = 0; c4 < 4; ++c4) w4[rt][r][c4] = ssh[bi][(l15 + 16 * c4) & 63];
    }
  float wdot = 0.f;

#pragma unroll
  for (int rt = 0; rt < 2; ++rt) {
    int ri0 = wave * 32 + rt * 16;
#pragma unroll
    for (int ct = 0; ct < 8; ++ct) {
      f32x4 d = {0.f, 0.f, 0.f, 0.f};
#pragma unroll
      for (int ks = 0; ks < KST; ++ks) {
        short8 bv = *(const short8*)(rz + (((ct * KST + ks) << 10) | (lane << 4)));
        d = __builtin_amdgcn_mfma_f32_16x16x32_bf16(af[rt][ks], bv, d, 0, 0, 0);
      }
      if (ri0 == ct * 16) {  // wave-uniform diag tile
#pragma unroll
        for (int r = 0; r < 4; ++r) {
          float dv = d[r];
          se[rt][r] += dlane[r] ? 0.f : exp2f(fmaf(dv, LOG2E, -B[rt][r]));
          wdot = fmaf(dlane[r] ? 0.f : w4[rt][r][ct & 3], dv, wdot);
        }
      } else {
#pragma unroll
        for (int r = 0; r < 4; ++r) {
          float dv = d[r];
          se[rt][r] += exp2f(fmaf(dv, LOG2E, -B[rt][r]));
          wdot = fmaf(w4[rt][r][ct & 3], dv, wdot);
        }
      }
    }
  }
  float tot = -wdot;
#pragma unroll
  for (int rt = 0; rt < 2; ++rt)
#pragma unroll
    for (int r = 0; r < 4; ++r) {
      float sv = se[rt][r];
#pragma unroll
      for (int off = 1; off < 16; off <<= 1) sv += __shfl_xor(sv, off);
      if (l15 == 0) {
        int bi = bi2[rt][r];
        float rw = 2.f * slrs[bi] - ssh[bi][bi];
        float lse = (__log2f(fmaxf(sv, 1e-37f)) + B[rt][r]) * LN2;
        tot += rw * lse;
      }
    }
  block_acc256(tot, scale, acc);
}

// final FC: lg[n,:] = a[n,:] @ wf + bf ; block per n, 1024 thr
__global__ void fc_k(const float* __restrict__ a, const float* __restrict__ wf,
                     const float* __restrict__ bf, float* __restrict__ lg) {
  int n = blockIdx.x;
  float accv[5] = {0.f, 0.f, 0.f, 0.f, 0.f};
  for (int f = threadIdx.x; f < 16640; f += 1024) {
    float av = a[(size_t)n * 16640 + f];
    const float* wr = wf + (size_t)f * 5;
#pragma unroll
    for (int k = 0; k < 5; ++k) accv[k] = fmaf(av, wr[k], accv[k]);
  }
  __shared__ float red[16][5];
#pragma unroll
  for (int k = 0; k < 5; ++k) {
    float v = accv[k];
#pragma unroll
    for (int off = 32; off; off >>= 1) v += __shfl_down(v, off);
    if ((threadIdx.x & 63) == 0) red[threadIdx.x >> 6][k] = v;
  }
  __syncthreads();
  if (threadIdx.x == 0) {
#pragma unroll
    for (int k = 0; k < 5; ++k) {
      float s = bf[k];
#pragma unroll
      for (int i = 0; i < 16; ++i) s += red[i][k];
      lg[n * 5 + k] = s;
    }
  }
}

__global__ void fin_k(const double* acc, float* out_loss) { *out_loss = (float)(*acc); }

extern "C" void kernel_launch(void* const* d_in, const int* in_sizes, int n_in,
                              void* d_out, int out_size, void* d_ws, size_t ws_size,
                              hipStream_t stream) {
  const float* aug[2] = {(const float*)d_in[0], (const float*)d_in[1]};
  const float* sl = (const float*)d_in[2];
  const float* wconv[3] = {(const float*)d_in[3], (const float*)d_in[6], (const float*)d_in[9]};
  const float* gam[3]   = {(const float*)d_in[4], (const float*)d_in[7], (const float*)d_in[10]};
  const float* bet[3]   = {(const float*)d_in[5], (const float*)d_in[8], (const float*)d_in[11]};
  const float* wf = (const float*)d_in[12];
  const float* bf = (const float*)d_in[13];
  float* out = (float*)d_out;
  float* ws = (float*)d_ws;
  if (ws_size < (size_t)WS_TOTAL * sizeof(float)) return;

  double* acc = (double*)(ws + WS_ACC);
  float* bnA = ws + WS_BNA;
  float* bnB = ws + WS_BNB;
  float* ftab = ws + WS_FTAB;
  float* roww = ws + WS_ROWW;
  float* slrs = ws + WS_SLRS;
  short* wbf[3] = {(short*)(ws + WS_WBF1), (short*)(ws + WS_WBF2), (short*)(ws + WS_WBF3)};
  float* partS = ws + WS_PART1;
  float* partS2 = ws + WS_PART2;
  float* normsP = ws + WS_PART1;   // alias: live only between norms_k and inst_b_k
  float* bmaxP = ws + WS_PART2;
  float* convb = ws + WS_CONV;
  __hip_bfloat16* zb16 = (__hip_bfloat16*)(ws + WS_ZB16);

  const int Cin[3]  = {1, 32, 64};
  const int Cout[3] = {32, 64, 128};
  const int Lin[3]  = {1024, 513, 258};
  const int Lc[3]   = {1025, 514, 259};
  const int Tarr[3] = {513, 258, 130};
  const float sig[3] = {2.f, 4.f, 8.f};
  const int Ktot[3] = {32, 256, 512};

  float* A1 = out + O_A1;
  float* A2 = out + O_A2;

  init_k<<<1, 64, 0, stream>>>(acc, sl, slrs);
  for (int d = 0; d < 3; ++d) {
    int total = Cout[d] * Ktot[d];
    wprep_k<<<(total + 255) / 256, 256, 0, stream>>>(wconv[d], wbf[d], Cin[d] * 8, Ktot[d], total);
  }

  for (int d = 0; d < 3; ++d) {
    int T = Tarr[d];
    int T2 = 2 * T;
    dim3 cg((Lc[d] + 63) / 64, BB);
    int nblk = cg.x * BB;
    for (int s = 0; s < 2; ++s) {
      const float* xin;
      float* pdst;
      if (d == 0)      { xin = aug[s];                               pdst = (s == 0) ? ws + WS_PA1 : ws + WS_PB1; }
      else if (d == 1) { xin = (s == 0) ? ws + WS_PA1 : ws + WS_PB1; pdst = (s == 0) ? ws + WS_PA2 : ws + WS_PB2; }
      else             { xin = (s == 0) ? ws + WS_PA2 : ws + WS_PB2; pdst = (s == 0) ? A1 : A2; }

      switch (d) {
        case 0: conv_mfma_k<1, 32, 4><<<cg, 256, 0, stream>>>(xin, wbf[0], convb, partS, partS2, Lin[d], Lc[d]); break;
        case 1: conv_mfma_k<32, 64, 16><<<cg, 256, 0, stream>>>(xin, wbf[1], convb, partS, partS2, Lin[d], Lc[d]); break;
        default: conv_mfma_k<64, 128, 16><<<cg, 256, 0, stream>>>(xin, wbf[2], convb, partS, partS2, Lin[d], Lc[d]); break;
      }
      stats2_k<<<Cout[d], 256, 0, stream>>>(partS, partS2, gam[d], bet[d], bnA, bnB, nblk, BB * Lc[d]);
      dim3 pg((T + 31) / 32, Cout[d] / 32, BB);
      pool_k<<<pg, dim3(32, 8), 0, stream>>>(convb, bnA, bnB, pdst, zb16, Cout[d], Lc[d], T, s * T);
    }
    ftab_k<<<1, 256, 0, stream>>>(ftab, roww, T, sig[d]);
    double scale = 0.5 / (128.0 * (double)T);
    dim3 tg((T2 + 63) / 64, BB);
    dim3 bg((T + 63) / 64, BB);
    switch (d) {
      case 0:
        norms_k<32><<<64, 1024, 0, stream>>>(zb16, normsP, bmaxP, T2);
        temp_b_k<32, 512><<<tg, 256, 0, stream>>>(zb16, roww, normsP, bmaxP, T, scale, acc);
        band_k<32><<<bg, 256, 0, stream>>>(zb16, ftab, T, scale, acc);
        inst_b_k<32><<<T, 256, 0, stream>>>(zb16, sl, slrs, normsP, T, scale, acc);
        break;
      case 1:
        norms_k<64><<<64, 1024, 0, stream>>>(zb16, normsP, bmaxP, T2);
        temp_b_k<64, 256><<<tg, 256, 0, stream>>>(zb16, roww, normsP, bmaxP, T, scale, acc);
        band_k<64><<<bg, 256, 0, stream>>>(zb16, ftab, T, scale, acc);
        inst_b_k<64><<<T, 256, 0, stream>>>(zb16, sl, slrs, normsP, T, scale, acc);
        break;
      default:
        norms_k<128><<<64, 1024, 0, stream>>>(zb16, normsP, bmaxP, T2);
        temp_b_k<128, 128><<<tg, 256, 0, stream>>>(zb16, roww, normsP, bmaxP, T, scale, acc);
        band_k<128><<<bg, 256, 0, stream>>>(zb16, ftab, T, scale, acc);
        inst_b_k<128><<<T, 256, 0, stream>>>(zb16, sl, slrs, normsP, T, scale, acc);
        break;
    }
  }
  fc_k<<<64, 1024, 0, stream>>>(A1, wf, bf, out + O_LG1);
  fc_k<<<64, 1024, 0, stream>>>(A2, wf, bf, out + O_LG2);
  fin_k<<<1, 1, 0, stream>>>(acc, out + O_LOSS);
}

// Round 11
// 331.202 us; speedup vs baseline: 8.9435x; 1.2181x over previous
//
#include <hip/hip_runtime.h>
#include <hip/hip_bf16.h>
#include <math.h>

#define BB 64
#define PB_STRIDE 1536      // >= 64 b * 17 jtiles
#define CONV_SIDE 2129920   // bf16 elems per side (64*128*260 max)

typedef __attribute__((ext_vector_type(8))) short short8;
typedef __attribute__((ext_vector_type(4))) short short4v;
typedef __attribute__((ext_vector_type(4))) float f32x4;

// workspace layout (floats)
#define WS_ACC    0
#define WS_BNA    8        // 256 (side-major: side*COUT+c)
#define WS_BNB    264      // 256
#define WS_FTAB   520      // 16
#define WS_ROWW   536      // 528
#define WS_SLRS   1064     // 64
#define WS_WBF1   1128     // 512
#define WS_WBF2   1640     // 8192
#define WS_WBF3   9832     // 32768
#define WS_PART1  42600    // 393216 (2*128*PB_STRIDE)
#define WS_PART2  435816   // 393216
#define WS_NORMS  829032   // 66560
#define WS_BMAX   895592   // 64
#define WS_CONV   895656   // 2129920 floats = 2 sides x CONV_SIDE bf16
#define WS_PA1    3025576
#define WS_PA2    4082344
#define WS_PB1    5139112
#define WS_PB2    6195880
#define WS_ZB16   7252648  // 1100000 floats
#define WS_TOTAL  8352648

// d_out layout (floats)
#define O_LG1  0
#define O_LG2  320
#define O_A1   640
#define O_A2   (640 + 1064960)
#define O_LOSS (O_A2 + 1064960)

#define LOG2E 1.44269504f
#define LN2   0.69314718f

__device__ __forceinline__ short f2bf(float f) {
  unsigned u = __float_as_uint(f);
  u += 0x7FFFu + ((u >> 16) & 1u);
  return (short)(u >> 16);
}
__device__ __forceinline__ float bfb2f(short s) {
  return __uint_as_float(((unsigned)(unsigned short)s) << 16);
}

__global__ void init_k(double* acc, const float* __restrict__ sl, float* __restrict__ slrs) {
  if (threadIdx.x == 0) *acc = 0.0;
  int r = threadIdx.x;
  float s = 0.f;
  for (int c = 0; c < 64; ++c) s += sl[r * 64 + c];
  slrs[r] = s;
}

__global__ void wprep_k(const float* __restrict__ w, short* __restrict__ wbf,
                        int nreal, int KTOT, int total) {
  int i = blockIdx.x * 256 + threadIdx.x;
  if (i >= total) return;
  int o = i / KTOT, q = i - o * KTOT;
  short v = 0;
  if (q < nreal) v = f2bf(w[o * nreal + q]);
  wbf[i] = v;
}

// ---------- fused-sides implicit-GEMM MFMA conv1d + BN partial stats ----------
// grid (jTiles, 128 = b + 64*side, OSPLIT). conv out stored bf16, padded stride Lcp.
template <int CIN, int COUT, int CHUNK_CI, int OSPLIT>
__launch_bounds__(256)
__global__ void conv2_k(const float* __restrict__ x1, const float* __restrict__ x2,
                        const short* __restrict__ wbf, short* __restrict__ ybf,
                        float* __restrict__ part_s, float* __restrict__ part_s2,
                        int Lin, int Lc, int Lcp) {
  constexpr int CIPAD = (CIN < 4) ? 4 : CIN;
  constexpr int KTOT = CIPAD * 8;
  constexpr int NCHUNK = CIPAD / CHUNK_CI;
  constexpr int ROWS8 = CHUNK_CI + 1;
  constexpr int COS = COUT / OSPLIT;
  constexpr int NT = COS / 16;
  __shared__ short8 a8[64 * ROWS8];
  __shared__ float ps[4][COS], ps2[4][COS];
  short* a_lds = (short*)a8;
  const int tid = threadIdx.x;
  const int wave = tid >> 6, lane = tid & 63, l15 = lane & 15, l4 = lane >> 4;
  const int by = blockIdx.y;
  const int b = by & 63, side = by >> 6;
  const int o0 = blockIdx.z * COS;
  const int j0 = blockIdx.x * 64;
  const float* xb = (side ? x2 : x1) + (size_t)b * CIN * Lin;
  short* yside = ybf + (size_t)side * CONV_SIDE;

  f32x4 acc[NT];
#pragma unroll
  for (int nt = 0; nt < NT; ++nt) acc[nt] = (f32x4){0.f, 0.f, 0.f, 0.f};

  for (int ch = 0; ch < NCHUNK; ++ch) {
    __syncthreads();
    for (int idx = tid; idx < 64 * CHUNK_CI; idx += 256) {
      int jr = idx & 63;
      int cc = idx >> 6;
      int ci = ch * CHUNK_CI + cc;
      short8 sv = (short8){0, 0, 0, 0, 0, 0, 0, 0};
      if (ci < CIN) {
        const float* xr = xb + (size_t)ci * Lin;
        int p0 = j0 + jr - 4;
#pragma unroll
        for (int k = 0; k < 8; ++k) {
          int p = p0 + k;
          float v = (p >= 0 && p < Lin) ? xr[p] : 0.f;
          sv[k] = f2bf(v);
        }
      }
      *(short8*)(a_lds + jr * (ROWS8 * 8) + cc * 8) = sv;
    }
    __syncthreads();
#pragma unroll
    for (int ks = 0; ks < CHUNK_CI / 4; ++ks) {
      short8 af = *(const short8*)(a_lds + (wave * 16 + l15) * (ROWS8 * 8) + ks * 32 + l4 * 8);
      const short* wrow = wbf + (size_t)(o0 + l15) * KTOT + (ch * CHUNK_CI * 8 + ks * 32 + l4 * 8);
#pragma unroll
      for (int nt = 0; nt < NT; ++nt) {
        short8 bv = *(const short8*)(wrow + (size_t)nt * 16 * KTOT);
        acc[nt] = __builtin_amdgcn_mfma_f32_16x16x32_bf16(af, bv, acc[nt], 0, 0, 0);
      }
    }
  }

  const int jbase = j0 + wave * 16 + l4 * 4;
#pragma unroll
  for (int nt = 0; nt < NT; ++nt) {
    int ol = nt * 16 + l15;
    size_t row = ((size_t)b * COUT + (o0 + ol)) * Lcp;
    float s = 0.f, s2 = 0.f;
    if (jbase + 3 < Lc) {
      short4v sv = (short4v){f2bf(acc[nt][0]), f2bf(acc[nt][1]), f2bf(acc[nt][2]), f2bf(acc[nt][3])};
      *(short4v*)(yside + row + jbase) = sv;
#pragma unroll
      for (int r = 0; r < 4; ++r) { float v = acc[nt][r]; s += v; s2 = fmaf(v, v, s2); }
    } else {
#pragma unroll
      for (int r = 0; r < 4; ++r) {
        if (jbase + r < Lc) {
          float v = acc[nt][r];
          yside[row + jbase + r] = f2bf(v);
          s += v; s2 = fmaf(v, v, s2);
        }
      }
    }
    s  += __shfl_xor(s, 16);  s  += __shfl_xor(s, 32);
    s2 += __shfl_xor(s2, 16); s2 += __shfl_xor(s2, 32);
    if (lane < 16) { ps[wave][ol] = s; ps2[wave][ol] = s2; }
  }
  __syncthreads();
  // per-(b, jtile) partial slot: RACE FIX — b must be part of the index
  int blk = b * gridDim.x + blockIdx.x;
  for (int o = tid; o < COS; o += 256) {
    size_t pi = (size_t)(side * COUT + o0 + o) * PB_STRIDE + blk;
    part_s [pi] = ps[0][o] + ps[1][o] + ps[2][o] + ps[3][o];
    part_s2[pi] = ps2[0][o] + ps2[1][o] + ps2[2][o] + ps2[3][o];
  }
}

// reduce conv partials -> bnA/bnB per (side, channel); grid 2*COUT
__global__ void stats2_k(const float* __restrict__ part_s, const float* __restrict__ part_s2,
                         const float* __restrict__ g, const float* __restrict__ beta,
                         float* __restrict__ bnA, float* __restrict__ bnB,
                         int nblk, int n, int COUT) {
  int bid = blockIdx.x;
  int c = bid % COUT;
  float s = 0.f, s2 = 0.f;
  for (int i = threadIdx.x; i < nblk; i += 256) {
    s += part_s[(size_t)bid * PB_STRIDE + i];
    s2 += part_s2[(size_t)bid * PB_STRIDE + i];
  }
#pragma unroll
  for (int off = 32; off; off >>= 1) { s += __shfl_down(s, off); s2 += __shfl_down(s2, off); }
  __shared__ float as[4], as2[4];
  if ((threadIdx.x & 63) == 0) { as[threadIdx.x >> 6] = s; as2[threadIdx.x >> 6] = s2; }
  __syncthreads();
  if (threadIdx.x == 0) {
    float S = as[0] + as[1] + as[2] + as[3];
    float S2 = as2[0] + as2[1] + as2[2] + as2[3];
    float fn = (float)n;
    float mu = S / fn;
    float var = S2 / fn - mu * mu;
    float A = g[c] * rsqrtf(var + 1e-5f);
    bnA[bid] = A;
    bnB[bid] = beta[c] - mu * A;
  }
}

// fused-sides BN-apply + ReLU + maxpool(2,2,pad1); grid (tTiles, C/32, 128)
__global__ void pool2_k(const short* __restrict__ convb, const float* __restrict__ bnA,
                        const float* __restrict__ bnB, float* __restrict__ pd1,
                        float* __restrict__ pd2, __hip_bfloat16* __restrict__ zb,
                        int C, int Lc, int Lcp, int Tout) {
  __shared__ float tile[32][33];
  int bz = blockIdx.z;
  int b = bz & 63, side = bz >> 6;
  const short* cs = convb + (size_t)side * CONV_SIDE;
  float* pooled = side ? pd2 : pd1;
  int zoff = side * Tout;
  int c0 = blockIdx.y * 32;
  int t0 = blockIdx.x * 32;
  int tx = threadIdx.x;
  int ty = threadIdx.y;
#pragma unroll
  for (int q = 0; q < 4; ++q) {
    int c = c0 + ty + q * 8;
    int t = t0 + tx;
    float v = 0.f;
    if (t < Tout) {
      const short* row = cs + ((size_t)b * C + c) * Lcp;
      float A = bnA[side * C + c], Bb = bnB[side * C + c];
      v = -3.0e38f;
      int p0 = 2 * t - 1;
      if (p0 >= 0) v = fmaxf(v, fmaxf(fmaf(A, bfb2f(row[p0]), Bb), 0.f));
      int p1 = 2 * t;
      if (p1 < Lc) v = fmaxf(v, fmaxf(fmaf(A, bfb2f(row[p1]), Bb), 0.f));
      pooled[((size_t)b * C + c) * Tout + t] = v;
    }
    tile[ty + q * 8][tx] = v;
  }
  __syncthreads();
  int T2 = 2 * Tout;
#pragma unroll
  for (int q = 0; q < 4; ++q) {
    int t = t0 + ty + q * 8;
    int c = c0 + tx;
    if (t < Tout)
      zb[((size_t)b * T2 + zoff + t) * (size_t)C + c] = __float2bfloat16(tile[tx][ty + q * 8]);
  }
}

// per-row norms of z + per-batch max norm; grid(B), 1024 thr
template <int C>
__global__ void norms_k(const __hip_bfloat16* __restrict__ zb, float* __restrict__ norms,
                        float* __restrict__ bmax, int T2) {
  int b = blockIdx.x;
  const __hip_bfloat16* zbb = zb + (size_t)b * T2 * C;
  int q = threadIdx.x & 3, r0 = threadIdx.x >> 2;
  float nm = 0.f;
  for (int r = r0; r < T2; r += 256) {
    float s = 0.f;
    const __hip_bfloat16* p = zbb + (size_t)r * C + q * (C / 4);
#pragma unroll
    for (int v = 0; v < C / 32; ++v) {
      short8 sv = *(const short8*)(p + v * 8);
#pragma unroll
      for (int e = 0; e < 8; ++e) { float f = bfb2f(sv[e]); s = fmaf(f, f, s); }
    }
    s += __shfl_xor(s, 1); s += __shfl_xor(s, 2);
    float nr = sqrtf(s);
    if (q == 0) norms[(size_t)b * T2 + r] = nr;
    nm = fmaxf(nm, nr);
  }
#pragma unroll
  for (int off = 32; off; off >>= 1) nm = fmaxf(nm, __shfl_xor(nm, off));
  __shared__ float pm[16];
  if ((threadIdx.x & 63) == 0) pm[threadIdx.x >> 6] = nm;
  __syncthreads();
  if (threadIdx.x == 0) {
    float m = 0.f;
#pragma unroll
    for (int i = 0; i < 16; ++i) m = fmaxf(m, pm[i]);
    bmax[b] = m;
  }
}

__global__ void ftab_k(float* __restrict__ ftab, float* __restrict__ roww, int T, float sigma) {
  __shared__ float fs[8];
  if (threadIdx.x < 8) {
    double mm = 2.0 / (1.0 + exp((double)threadIdx.x * (double)sigma));
    float f = (mm < 1e-6) ? 0.f : (float)mm;
    ftab[threadIdx.x] = f; fs[threadIdx.x] = f;
  }
  __syncthreads();
  for (int i = threadIdx.x; i < T; i += blockDim.x) {
    float s = fs[0];
#pragma unroll
    for (int d = 1; d < 8; ++d) s += fs[d] * ((i >= d ? 1.f : 0.f) + (i + d < T ? 1.f : 0.f));
    roww[i] = 2.f * s - fs[0];
  }
}

__device__ __forceinline__ void block_acc256(float v, double scale, double* acc) {
#pragma unroll
  for (int off = 32; off; off >>= 1) v += __shfl_down(v, off);
  __shared__ float part[4];
  if ((threadIdx.x & 63) == 0) part[threadIdx.x >> 6] = v;
  __syncthreads();
  if (threadIdx.x == 0)
    atomicAdd(acc, (double)(part[0] + part[1] + part[2] + part[3]) * scale);
}

// ---------- biased-exp2 one-pass MFMA temporal contrastive ----------
template <int C, int NC>
__launch_bounds__(256)
__global__ void temp_b_k(const __hip_bfloat16* __restrict__ zb, const float* __restrict__ roww,
                         const float* __restrict__ norms, const float* __restrict__ bmax,
                         int T, double scale, double* __restrict__ acc) {
  constexpr int KST = C / 32;
  constexpr int LOGK = (KST == 1) ? 0 : (KST == 2) ? 1 : 2;
  __shared__ float4 colz4[NC * C / 8];
  char* colz = (char*)colz4;
  const int tid = threadIdx.x;
  const int wave = tid >> 6, lane = tid & 63, l15 = lane & 15, l4 = lane >> 4;
  const int b = blockIdx.y;
  const int T2 = 2 * T;
  const int T2pad = ((T2 + 15) >> 4) << 4;
  const int i0 = blockIdx.x * 64 + wave * 16;
  const __hip_bfloat16* zbb = zb + (size_t)b * T2 * C;

  short8 af[KST];
  {
    int ar = i0 + l15; if (ar > T2 - 1) ar = T2 - 1;
#pragma unroll
    for (int ks = 0; ks < KST; ++ks)
      af[ks] = *(const short8*)(zbb + (size_t)ar * C + ks * 32 + l4 * 8);
  }
  const float Nb = bmax[b];
  float B[4], se[4];
  int ig[4]; bool dlane[4];
#pragma unroll
  for (int r = 0; r < 4; ++r) {
    ig[r] = i0 + l4 * 4 + r;
    int ix = ig[r] < T2 ? ig[r] : T2 - 1;
    B[r] = fmaxf(norms[(size_t)b * T2 + ix] * Nb * LOG2E - 110.f, 0.f);
    se[r] = 0.f;
    dlane[r] = (l15 == l4 * 4 + r);
  }

  for (int cb = 0; cb < T2pad; cb += NC) {
    int rows = T2pad - cb; if (rows > NC) rows = NC;
    __syncthreads();
    for (int idx = tid; idx < rows * (C / 8); idx += 256) {
      int ln = idx & 63;
      int ks = (idx >> 6) & (KST - 1);
      int ct = idx >> (6 + LOGK);
      int gr = cb + ct * 16 + (ln & 15);
      short8 sv = (short8){0, 0, 0, 0, 0, 0, 0, 0};
      if (gr < T2) sv = *(const short8*)(zbb + (size_t)gr * C + ks * 32 + (ln >> 4) * 8);
      *(short8*)(colz + (size_t)idx * 16) = sv;
    }
    __syncthreads();
    int ntiles = rows >> 4;
    for (int ct = 0; ct < ntiles; ++ct) {
      int cj0 = cb + ct * 16;
      f32x4 d = {0.f, 0.f, 0.f, 0.f};
#pragma unroll
      for (int ks = 0; ks < KST; ++ks) {
        short8 bv = *(const short8*)(colz + (((ct * KST + ks) << 10) | (lane << 4)));
        d = __builtin_amdgcn_mfma_f32_16x16x32_bf16(af[ks], bv, d, 0, 0, 0);
      }
      if (cj0 == i0) {  // wave-uniform diag tile
#pragma unroll
        for (int r = 0; r < 4; ++r)
          se[r] += dlane[r] ? 0.f : exp2f(fmaf(d[r], LOG2E, -B[r]));
      } else {
#pragma unroll
        for (int r = 0; r < 4; ++r)
          se[r] += exp2f(fmaf(d[r], LOG2E, -B[r]));
      }
    }
  }

  const float npad = (float)(T2pad - T2);
  float tot = 0.f;
#pragma unroll
  for (int r = 0; r < 4; ++r) {
    float sv = se[r];
#pragma unroll
    for (int off = 1; off < 16; off <<= 1) sv += __shfl_xor(sv, off);
    sv -= npad * exp2f(-B[r]);   // pad columns: s=0 -> exactly 2^-B each
    if (l15 == 0 && ig[r] < T2) {
      int ii = ig[r] < T ? ig[r] : ig[r] - T;
      float lse = (__log2f(fmaxf(sv, 1e-37f)) + B[r]) * LN2;
      tot += roww[ii] * lse;
    }
  }
  block_acc256(tot, scale, acc);
}

// ---------- band wdot for temporal loss ----------
template <int C>
__launch_bounds__(256)
__global__ void band_k(const __hip_bfloat16* __restrict__ zb, const float* __restrict__ ftab,
                       int T, double scale, double* __restrict__ acc) {
  __shared__ float y[78][C + 1];
  __shared__ float f[8];
  const int tid = threadIdx.x;
  const int b = blockIdx.y, ii0 = blockIdx.x * 64;
  const int T2 = 2 * T;
  if (tid < 8) f[tid] = ftab[tid];
  const __hip_bfloat16* zbb = zb + (size_t)b * T2 * C;
  for (int idx = tid; idx < 78 * C; idx += 256) {
    int rr = idx / C, k = idx - rr * C;
    int ii = ii0 - 7 + rr;
    float v = 0.f;
    if (ii >= 0 && ii < T)
      v = __bfloat162float(zbb[(size_t)ii * C + k]) +
          __bfloat162float(zbb[(size_t)(T + ii) * C + k]);
    y[rr][k] = v;
  }
  float p2 = 0.f;
  for (int idx = tid; idx < 64 * C; idx += 256) {
    int rr = idx / C, k = idx - rr * C;
    int ii = ii0 + rr;
    if (ii < T) {
      float v1 = __bfloat162float(zbb[(size_t)ii * C + k]);
      float v2 = __bfloat162float(zbb[(size_t)(T + ii) * C + k]);
      p2 = fmaf(v1, v1, p2); p2 = fmaf(v2, v2, p2);
    }
  }
  __syncthreads();
  const int m = tid & 63, q = tid >> 6;
  float p = 0.f;
  if (ii0 + m < T) {
    int rr = m + 7;
    constexpr int SL = C / 4;
    for (int k = q * SL; k < (q + 1) * SL; ++k) {
      float g = f[0] * y[rr][k];
#pragma unroll
      for (int dd = 1; dd < 8; ++dd) g = fmaf(f[dd], y[rr - dd][k] + y[rr + dd][k], g);
      p = fmaf(y[rr][k], g, p);
    }
  }
  block_acc256(f[0] * p2 - p, scale, acc);
}

// ---------- biased-exp2 instance contrastive ----------
template <int C>
__launch_bounds__(256)
__global__ void inst_b_k(const __hip_bfloat16* __restrict__ zb, const float* __restrict__ sl,
                         const float* __restrict__ slrs, const float* __restrict__ norms,
                         int T, double scale, double* __restrict__ acc) {
  constexpr int KST = C / 32;
  constexpr int LOGK = (KST == 1) ? 0 : (KST == 2) ? 1 : 2;
  __shared__ float4 rz4[128 * C / 8];
  __shared__ float ssh[64][65];
  __shared__ float normsh[128];
  __shared__ float pmx[4];
  char* rz = (char*)rz4;
  const int tid = threadIdx.x;
  const int wave = tid >> 6, lane = tid & 63, l15 = lane & 15, l4 = lane >> 4;
  const int t = blockIdx.x;
  const int T2 = 2 * T;
  for (int idx = tid; idx < 128 * (C / 8); idx += 256) {
    int ln = idx & 63;
    int ks = (idx >> 6) & (KST - 1);
    int t16 = idx >> (6 + LOGK);
    int r = t16 * 16 + (ln & 15);
    size_t grow = (size_t)(r & 63) * T2 + ((r < 64) ? t : T + t);
    *(short8*)(rz + (size_t)idx * 16) = *(const short8*)(zb + grow * C + ks * 32 + (ln >> 4) * 8);
  }
  for (int u = tid; u < 4096; u += 256) ssh[u >> 6][u & 63] = sl[u];
  if (tid < 128) normsh[tid] = norms[(size_t)(tid & 63) * T2 + ((tid < 64) ? t : T + t)];
  __syncthreads();
  float nv = (tid < 128) ? normsh[tid] : 0.f;
#pragma unroll
  for (int off = 32; off; off >>= 1) nv = fmaxf(nv, __shfl_xor(nv, off));
  if (lane == 0) pmx[wave] = nv;
  __syncthreads();
  const float Nt = fmaxf(fmaxf(pmx[0], pmx[1]), fmaxf(pmx[2], pmx[3]));

  short8 af[2][KST];
#pragma unroll
  for (int rt = 0; rt < 2; ++rt)
#pragma unroll
    for (int ks = 0; ks < KST; ++ks)
      af[rt][ks] = *(const short8*)(rz + ((((wave * 2 + rt) * KST + ks) << 10) | (lane << 4)));
  float B[2][4], se[2][4], w4[2][4][4];
  int bi2[2][4]; bool dlane[4];
#pragma unroll
  for (int r = 0; r < 4; ++r) dlane[r] = (l15 == l4 * 4 + r);
#pragma unroll
  for (int rt = 0; rt < 2; ++rt)
#pragma unroll
    for (int r = 0; r < 4; ++r) {
      int igv = wave * 32 + rt * 16 + l4 * 4 + r;
      int bi = igv & 63;
      B[rt][r] = fmaxf(normsh[igv] * Nt * LOG2E - 110.f, 0.f);
      se[rt][r] = 0.f;
      bi2[rt][r] = bi;
#pragma unroll
      for (int c4 = 0; c4 < 4; ++c4) w4[rt][r][c4] = ssh[bi][(l15 + 16 * c4) & 63];
    }
  float wdot = 0.f;

#pragma unroll
  for (int rt = 0; rt < 2; ++rt) {
    int ri0 = wave * 32 + rt * 16;
#pragma unroll
    for (int ct = 0; ct < 8; ++ct) {
      f32x4 d = {0.f, 0.f, 0.f, 0.f};
#pragma unroll
      for (int ks = 0; ks < KST; ++ks) {
        short8 bv = *(const short8*)(rz + (((ct * KST + ks) << 10) | (lane << 4)));
        d = __builtin_amdgcn_mfma_f32_16x16x32_bf16(af[rt][ks], bv, d, 0, 0, 0);
      }
      if (ri0 == ct * 16) {
#pragma unroll
        for (int r = 0; r < 4; ++r) {
          float dv = d[r];
          se[rt][r] += dlane[r] ? 0.f : exp2f(fmaf(dv, LOG2E, -B[rt][r]));
          wdot = fmaf(dlane[r] ? 0.f : w4[rt][r][ct & 3], dv, wdot);
        }
      } else {
#pragma unroll
        for (int r = 0; r < 4; ++r) {
          float dv = d[r];
          se[rt][r] += exp2f(fmaf(dv, LOG2E, -B[rt][r]));
          wdot = fmaf(w4[rt][r][ct & 3], dv, wdot);
        }
      }
    }
  }
  float tot = -wdot;
#pragma unroll
  for (int rt = 0; rt < 2; ++rt)
#pragma unroll
    for (int r = 0; r < 4; ++r) {
      float sv = se[rt][r];
#pragma unroll
      for (int off = 1; off < 16; off <<= 1) sv += __shfl_xor(sv, off);
      if (l15 == 0) {
        int bi = bi2[rt][r];
        float rw = 2.f * slrs[bi] - ssh[bi][bi];
        float lse = (__log2f(fmaxf(sv, 1e-37f)) + B[rt][r]) * LN2;
        tot += rw * lse;
      }
    }
  block_acc256(tot, scale, acc);
}

// final FC: lg[n,:] = a[n,:] @ wf + bf
__global__ void fc_k(const float* __restrict__ a, const float* __restrict__ wf,
                     const float* __restrict__ bf, float* __restrict__ lg) {
  int n = blockIdx.x;
  float accv[5] = {0.f, 0.f, 0.f, 0.f, 0.f};
  for (int f = threadIdx.x; f < 16640; f += 1024) {
    float av = a[(size_t)n * 16640 + f];
    const float* wr = wf + (size_t)f * 5;
#pragma unroll
    for (int k = 0; k < 5; ++k) accv[k] = fmaf(av, wr[k], accv[k]);
  }
  __shared__ float red[16][5];
#pragma unroll
  for (int k = 0; k < 5; ++k) {
    float v = accv[k];
#pragma unroll
    for (int off = 32; off; off >>= 1) v += __shfl_down(v, off);
    if ((threadIdx.x & 63) == 0) red[threadIdx.x >> 6][k] = v;
  }
  __syncthreads();
  if (threadIdx.x == 0) {
#pragma unroll
    for (int k = 0; k < 5; ++k) {
      float s = bf[k];
#pragma unroll
      for (int i = 0; i < 16; ++i) s += red[i][k];
      lg[n * 5 + k] = s;
    }
  }
}

__global__ void fin_k(const double* acc, float* out_loss) { *out_loss = (float)(*acc); }

extern "C" void kernel_launch(void* const* d_in, const int* in_sizes, int n_in,
                              void* d_out, int out_size, void* d_ws, size_t ws_size,
                              hipStream_t stream) {
  const float* aug1 = (const float*)d_in[0];
  const float* aug2 = (const float*)d_in[1];
  const float* sl = (const float*)d_in[2];
  const float* wconv[3] = {(const float*)d_in[3], (const float*)d_in[6], (const float*)d_in[9]};
  const float* gam[3]   = {(const float*)d_in[4], (const float*)d_in[7], (const float*)d_in[10]};
  const float* bet[3]   = {(const float*)d_in[5], (const float*)d_in[8], (const float*)d_in[11]};
  const float* wf = (const float*)d_in[12];
  const float* bf = (const float*)d_in[13];
  float* out = (float*)d_out;
  float* ws = (float*)d_ws;
  if (ws_size < (size_t)WS_TOTAL * sizeof(float)) return;

  double* acc = (double*)(ws + WS_ACC);
  float* bnA = ws + WS_BNA;
  float* bnB = ws + WS_BNB;
  float* ftab = ws + WS_FTAB;
  float* roww = ws + WS_ROWW;
  float* slrs = ws + WS_SLRS;
  short* wbf[3] = {(short*)(ws + WS_WBF1), (short*)(ws + WS_WBF2), (short*)(ws + WS_WBF3)};
  float* partS = ws + WS_PART1;
  float* partS2 = ws + WS_PART2;
  float* normsP = ws + WS_NORMS;
  float* bmaxP = ws + WS_BMAX;
  short* convb = (short*)(ws + WS_CONV);
  __hip_bfloat16* zb16 = (__hip_bfloat16*)(ws + WS_ZB16);

  const int Cin[3]  = {1, 32, 64};
  const int Cout[3] = {32, 64, 128};
  const int Lin[3]  = {1024, 513, 258};
  const int Lc[3]   = {1025, 514, 259};
  const int Lcp[3]  = {1028, 516, 260};
  const int Tarr[3] = {513, 258, 130};
  const float sig[3] = {2.f, 4.f, 8.f};
  const int Ktot[3] = {32, 256, 512};

  float* A1 = out + O_A1;
  float* A2 = out + O_A2;

  init_k<<<1, 64, 0, stream>>>(acc, sl, slrs);
  for (int d = 0; d < 3; ++d) {
    int total = Cout[d] * Ktot[d];
    wprep_k<<<(total + 255) / 256, 256, 0, stream>>>(wconv[d], wbf[d], Cin[d] * 8, Ktot[d], total);
  }

  for (int d = 0; d < 3; ++d) {
    int T = Tarr[d];
    int T2 = 2 * T;
    int jt = (Lc[d] + 63) / 64;
    const float* x1; const float* x2; float* p1; float* p2;
    if (d == 0)      { x1 = aug1;         x2 = aug2;         p1 = ws + WS_PA1; p2 = ws + WS_PB1; }
    else if (d == 1) { x1 = ws + WS_PA1;  x2 = ws + WS_PB1;  p1 = ws + WS_PA2; p2 = ws + WS_PB2; }
    else             { x1 = ws + WS_PA2;  x2 = ws + WS_PB2;  p1 = A1;          p2 = A2; }

    switch (d) {
      case 0: conv2_k<1, 32, 4, 1><<<dim3(jt, 128, 1), 256, 0, stream>>>(x1, x2, wbf[0], convb, partS, partS2, Lin[d], Lc[d], Lcp[d]); break;
      case 1: conv2_k<32, 64, 16, 1><<<dim3(jt, 128, 1), 256, 0, stream>>>(x1, x2, wbf[1], convb, partS, partS2, Lin[d], Lc[d], Lcp[d]); break;
      default: conv2_k<64, 128, 16, 2><<<dim3(jt, 128, 2), 256, 0, stream>>>(x1, x2, wbf[2], convb, partS, partS2, Lin[d], Lc[d], Lcp[d]); break;
    }
    stats2_k<<<2 * Cout[d], 256, 0, stream>>>(partS, partS2, gam[d], bet[d], bnA, bnB, 64 * jt, BB * Lc[d], Cout[d]);
    pool2_k<<<dim3((T + 31) / 32, Cout[d] / 32, 128), dim3(32, 8), 0, stream>>>(convb, bnA, bnB, p1, p2, zb16, Cout[d], Lc[d], Lcp[d], T);

    ftab_k<<<1, 256, 0, stream>>>(ftab, roww, T, sig[d]);
    double scale = 0.5 / (128.0 * (double)T);
    dim3 tg((T2 + 63) / 64, BB);
    dim3 bg((T + 63) / 64, BB);
    switch (d) {
      case 0:
        norms_k<32><<<64, 1024, 0, stream>>>(zb16, normsP, bmaxP, T2);
        temp_b_k<32, 512><<<tg, 256, 0, stream>>>(zb16, roww, normsP, bmaxP, T, scale, acc);
        band_k<32><<<bg, 256, 0, stream>>>(zb16, ftab, T, scale, acc);
        inst_b_k<32><<<T, 256, 0, stream>>>(zb16, sl, slrs, normsP, T, scale, acc);
        break;
      case 1:
        norms_k<64><<<64, 1024, 0, stream>>>(zb16, normsP, bmaxP, T2);
        temp_b_k<64, 256><<<tg, 256, 0, stream>>>(zb16, roww, normsP, bmaxP, T, scale, acc);
        band_k<64><<<bg, 256, 0, stream>>>(zb16, ftab, T, scale, acc);
        inst_b_k<64><<<T, 256, 0, stream>>>(zb16, sl, slrs, normsP, T, scale, acc);
        break;
      default:
        norms_k<128><<<64, 1024, 0, stream>>>(zb16, normsP, bmaxP, T2);
        temp_b_k<128, 128><<<tg, 256, 0, stream>>>(zb16, roww, normsP, bmaxP, T, scale, acc);
        band_k<128><<<bg, 256, 0, stream>>>(zb16, ftab, T, scale, acc);
        inst_b_k<128><<<T, 256, 0, stream>>>(zb16, sl, slrs, normsP, T, scale, acc);
        break;
    }
  }
  fc_k<<<64, 1024, 0, stream>>>(A1, wf, bf, out + O_LG1);
  fc_k<<<64, 1024, 0, stream>>>(A2, wf, bf, out + O_LG2);
  fin_k<<<1, 1, 0, stream>>>(acc, out + O_LOSS);
}